// Round 1
// baseline (4744.051 us; speedup 1.0000x reference)
//
#include <hip/hip_runtime.h>
#include <hip/hip_bf16.h>
#include <math.h>

#define NN 500000
#define NE 1000000
#define FD 128
#define LDIM 8
#define OPC 5000
#define TN 32   // nodes per block tile (500000 % 32 == 0 -> 15625 blocks)

// ---------------- enc1: h = relu(feats @ W1 + b1) ----------------
__global__ __launch_bounds__(128) void enc1_kernel(
    const int* __restrict__ op_id, const int* __restrict__ sv_id, const int* __restrict__ st_id,
    const float* __restrict__ lat,
    const float* __restrict__ opE, const float* __restrict__ svE, const float* __restrict__ stE,
    const float* __restrict__ W1, const float* __restrict__ b1,
    float* __restrict__ h)
{
    __shared__ float4 feats4[TN * 50];   // 32 nodes x 200 floats = 25.6 KB
    __shared__ int ids[3 * TN];
    const int tid = threadIdx.x;
    const int base = blockIdx.x * TN;

    if (tid < TN) {
        int n = base + tid;
        ids[tid]          = op_id[n];
        ids[TN + tid]     = sv_id[n];
        ids[2 * TN + tid] = st_id[n];
    }
    __syncthreads();

    const float4* opE4 = (const float4*)opE;
    const float4* svE4 = (const float4*)svE;
    const float4* stE4 = (const float4*)stE;
    const float4* lat4 = (const float4*)lat;

    for (int idx = tid; idx < TN * 50; idx += 128) {
        int t = idx / 50, j = idx % 50;
        float4 v;
        if (j < 16)      v = opE4[(size_t)ids[t] * 16 + j];
        else if (j < 32) v = svE4[(size_t)ids[TN + t] * 16 + (j - 16)];
        else if (j < 48) v = stE4[(size_t)ids[2 * TN + t] * 16 + (j - 32)];
        else             v = lat4[(size_t)(base + t) * 2 + (j - 48)];
        feats4[t * 50 + j] = v;
    }
    __syncthreads();

    const int f = tid;
    float acc[TN];
    {
        float bb = b1[f];
        #pragma unroll
        for (int t = 0; t < TN; t++) acc[t] = bb;
    }
    for (int k4 = 0; k4 < 50; k4++) {
        float w0 = W1[(k4 * 4 + 0) * FD + f];
        float w1 = W1[(k4 * 4 + 1) * FD + f];
        float w2 = W1[(k4 * 4 + 2) * FD + f];
        float w3 = W1[(k4 * 4 + 3) * FD + f];
        #pragma unroll
        for (int t = 0; t < TN; t++) {
            float4 v = feats4[t * 50 + k4];
            acc[t] = fmaf(v.x, w0, acc[t]);
            acc[t] = fmaf(v.y, w1, acc[t]);
            acc[t] = fmaf(v.z, w2, acc[t]);
            acc[t] = fmaf(v.w, w3, acc[t]);
        }
    }
    #pragma unroll
    for (int t = 0; t < TN; t++)
        h[(size_t)(base + t) * FD + f] = fmaxf(acc[t], 0.0f);
}

// ---------------- enc2: y = h @ W2 + b2; z = mu + exp(.5*tanh(lv))*eps; KL ----------------
__global__ __launch_bounds__(256) void enc2_kernel(
    const float* __restrict__ h, const float* __restrict__ W2, const float* __restrict__ b2,
    const float* __restrict__ eps, float* __restrict__ z, float* __restrict__ kl_sum)
{
    __shared__ float4 ht4[TN * 32];   // 16 KB; reused as zlv[TN][128] afterwards
    const int tid = threadIdx.x;
    const int base = blockIdx.x * TN;

    const float4* h4 = (const float4*)h;
    for (int idx = tid; idx < TN * 32; idx += 256)
        ht4[idx] = h4[(size_t)base * 32 + idx];
    __syncthreads();

    const int f = tid;  // 0..255 output column of y
    float acc[TN];
    {
        float bb = b2[f];
        #pragma unroll
        for (int t = 0; t < TN; t++) acc[t] = bb;
    }
    for (int k4 = 0; k4 < 32; k4++) {
        float w0 = W2[(k4 * 4 + 0) * 256 + f];
        float w1 = W2[(k4 * 4 + 1) * 256 + f];
        float w2 = W2[(k4 * 4 + 2) * 256 + f];
        float w3 = W2[(k4 * 4 + 3) * 256 + f];
        #pragma unroll
        for (int t = 0; t < TN; t++) {
            float4 v = ht4[t * 32 + k4];
            acc[t] = fmaf(v.x, w0, acc[t]);
            acc[t] = fmaf(v.y, w1, acc[t]);
            acc[t] = fmaf(v.z, w2, acc[t]);
            acc[t] = fmaf(v.w, w3, acc[t]);
        }
    }
    __syncthreads();  // ht4 dead, reuse as zlv
    float* zlv = (float*)ht4;
    if (f >= 128) {
        int fc = f - 128;
        #pragma unroll
        for (int t = 0; t < TN; t++)
            zlv[t * FD + fc] = tanhf(acc[t]);
    }
    __syncthreads();

    float klloc = 0.0f;
    if (f < 128) {
        #pragma unroll
        for (int t = 0; t < TN; t++) {
            float zmu = acc[t];
            float lv  = zlv[t * FD + f];
            float e   = eps[(size_t)(base + t) * FD + f];
            z[(size_t)(base + t) * FD + f] = zmu + expf(0.5f * lv) * e;
            klloc += lv + 1.0f - expf(lv) - zmu * zmu;
        }
    }
    #pragma unroll
    for (int off = 32; off > 0; off >>= 1) klloc += __shfl_down(klloc, off);
    if ((tid & 63) == 0) atomicAdd(kl_sum, klloc);
}

// ---------------- scatter: agg[dst] += z[src] ----------------
__global__ __launch_bounds__(256) void scatter_kernel(
    const int* __restrict__ esrc, const int* __restrict__ edst,
    const float* __restrict__ z, float* __restrict__ agg)
{
    int gid = blockIdx.x * 256 + threadIdx.x;
    int e = gid >> 5, l = gid & 31;
    int s = esrc[e], d = edst[e];
    float4 v = ((const float4*)z)[(size_t)s * 32 + l];
    float* ap = agg + (size_t)d * FD + l * 4;
    atomicAdd(ap + 0, v.x);
    atomicAdd(ap + 1, v.y);
    atomicAdd(ap + 2, v.z);
    atomicAdd(ap + 3, v.w);
}

// ---------------- dec: yd=relu(z@Wself+agg@Wagg); heads; loss; segment sums ----------------
__global__ __launch_bounds__(128) void dec_kernel(
    const float* __restrict__ z, const float* __restrict__ agg,
    const float* __restrict__ Wself, const float* __restrict__ Wagg,
    const float* __restrict__ muW, const float* __restrict__ mub,
    const float* __restrict__ lvW, const float* __restrict__ lvb,
    const float* __restrict__ opwise, const int* __restrict__ op_id,
    const float* __restrict__ lat,
    float* __restrict__ op_loss, float* __restrict__ op_cnt,
    float* __restrict__ loss_sum)
{
    __shared__ float4 zt4[TN * 32];      // 16 KB
    __shared__ float4 at4[TN * 32];      // 16 KB
    __shared__ float  ydl[TN * 129];     // padded, 16.5 KB
    __shared__ float  mul_s[TN * 8], lvl_s[TN * 8];

    const int tid = threadIdx.x;
    const int base = blockIdx.x * TN;

    const float4* z4 = (const float4*)z;
    const float4* a4 = (const float4*)agg;
    for (int idx = tid; idx < TN * 32; idx += 128) {
        zt4[idx] = z4[(size_t)base * 32 + idx];
        at4[idx] = a4[(size_t)base * 32 + idx];
    }
    __syncthreads();

    const int f = tid;  // 0..127
    float acc[TN];
    #pragma unroll
    for (int t = 0; t < TN; t++) acc[t] = 0.0f;
    for (int k4 = 0; k4 < 32; k4++) {
        float s0 = Wself[(k4 * 4 + 0) * FD + f];
        float s1 = Wself[(k4 * 4 + 1) * FD + f];
        float s2 = Wself[(k4 * 4 + 2) * FD + f];
        float s3 = Wself[(k4 * 4 + 3) * FD + f];
        float a0 = Wagg [(k4 * 4 + 0) * FD + f];
        float a1 = Wagg [(k4 * 4 + 1) * FD + f];
        float a2 = Wagg [(k4 * 4 + 2) * FD + f];
        float a3 = Wagg [(k4 * 4 + 3) * FD + f];
        #pragma unroll
        for (int t = 0; t < TN; t++) {
            float4 v = zt4[t * 32 + k4];
            float4 u = at4[t * 32 + k4];
            acc[t] = fmaf(v.x, s0, acc[t]);
            acc[t] = fmaf(v.y, s1, acc[t]);
            acc[t] = fmaf(v.z, s2, acc[t]);
            acc[t] = fmaf(v.w, s3, acc[t]);
            acc[t] = fmaf(u.x, a0, acc[t]);
            acc[t] = fmaf(u.y, a1, acc[t]);
            acc[t] = fmaf(u.z, a2, acc[t]);
            acc[t] = fmaf(u.w, a3, acc[t]);
        }
    }
    #pragma unroll
    for (int t = 0; t < TN; t++)
        ydl[t * 129 + f] = fmaxf(acc[t], 0.0f);
    __syncthreads();

    // mu/lv heads: thread -> (t, l), two halves of the node tile
    for (int half = 0; half < 2; half++) {
        int t = half * 16 + (tid >> 3);
        int l = tid & 7;
        float ma = mub[l], la = lvb[l];
        for (int k = 0; k < FD; k++) {
            float yv = ydl[t * 129 + k];
            ma = fmaf(yv, muW[k * 8 + l], ma);
            la = fmaf(yv, lvW[k * 8 + l], la);
        }
        mul_s[t * 8 + l] = ma;
        lvl_s[t * 8 + l] = la;
    }
    __syncthreads();

    float lsum = 0.0f;
    if (tid < TN) {
        int t = tid;
        int n = base + t;
        int op = op_id[n];
        const float4* w4 = (const float4*)(opwise + (size_t)op * 128);
        float mout[8], lout[8];
        #pragma unroll
        for (int k = 0; k < 8; k++) { mout[k] = 0.0f; lout[k] = 0.0f; }
        #pragma unroll
        for (int l = 0; l < 8; l++) {
            float m = mul_s[t * 8 + l];
            float v = lvl_s[t * 8 + l];
            float4 a = w4[l * 4 + 0];
            float4 b = w4[l * 4 + 1];
            float4 c = w4[l * 4 + 2];
            float4 d = w4[l * 4 + 3];
            mout[0] = fmaf(m, a.x, mout[0]); mout[1] = fmaf(m, a.y, mout[1]);
            mout[2] = fmaf(m, a.z, mout[2]); mout[3] = fmaf(m, a.w, mout[3]);
            mout[4] = fmaf(m, b.x, mout[4]); mout[5] = fmaf(m, b.y, mout[5]);
            mout[6] = fmaf(m, b.z, mout[6]); mout[7] = fmaf(m, b.w, mout[7]);
            lout[0] = fmaf(v, c.x, lout[0]); lout[1] = fmaf(v, c.y, lout[1]);
            lout[2] = fmaf(v, c.z, lout[2]); lout[3] = fmaf(v, c.w, lout[3]);
            lout[4] = fmaf(v, d.x, lout[4]); lout[5] = fmaf(v, d.y, lout[5]);
            lout[6] = fmaf(v, d.z, lout[6]); lout[7] = fmaf(v, d.w, lout[7]);
        }
        float lnode = 0.0f;
        #pragma unroll
        for (int k = 0; k < 8; k++) {
            float label = lat[(size_t)n * 8 + k];
            float diff  = mout[k] - label;
            lnode += diff * diff / (2.0f * expf(lout[k]) + 1e-7f) + 0.5f * lout[k];
        }
        lnode *= 0.125f;
        atomicAdd(&op_loss[op], lnode);
        atomicAdd(&op_cnt[op], 1.0f);
        lsum = lnode;
    }
    #pragma unroll
    for (int off = 32; off > 0; off >>= 1) lsum += __shfl_down(lsum, off);
    if ((tid & 63) == 0) atomicAdd(loss_sum, lsum);
}

// ---------------- finalize: total = loss_sum/N - 0.5*kl_sum/(N*128) ----------------
__global__ void final_kernel(const float* __restrict__ accum, float* __restrict__ out)
{
    out[0] = accum[1] / (float)NN - 0.5f * (accum[0] / (float)((size_t)NN * 128));
}

extern "C" void kernel_launch(void* const* d_in, const int* in_sizes, int n_in,
                              void* d_out, int out_size, void* d_ws, size_t ws_size,
                              hipStream_t stream) {
    const int*   op_id  = (const int*)  d_in[0];
    const int*   sv_id  = (const int*)  d_in[1];
    const int*   st_id  = (const int*)  d_in[2];
    const float* lat    = (const float*)d_in[3];
    const int*   esrc   = (const int*)  d_in[4];
    const int*   edst   = (const int*)  d_in[5];
    const float* eps    = (const float*)d_in[6];
    const float* opE    = (const float*)d_in[7];
    const float* svE    = (const float*)d_in[8];
    const float* stE    = (const float*)d_in[9];
    const float* W1     = (const float*)d_in[10];
    const float* b1     = (const float*)d_in[11];
    const float* W2     = (const float*)d_in[12];
    const float* b2     = (const float*)d_in[13];
    const float* Wself  = (const float*)d_in[14];
    const float* Wagg   = (const float*)d_in[15];
    const float* muW    = (const float*)d_in[16];
    const float* mub    = (const float*)d_in[17];
    const float* lvW    = (const float*)d_in[18];
    const float* lvb    = (const float*)d_in[19];
    const float* opwise = (const float*)d_in[20];

    float* ws    = (float*)d_ws;
    float* h_buf = ws;                              // N*128 floats (reused as agg)
    float* z_buf = ws + (size_t)NN * FD;            // N*128 floats
    float* accum = ws + 2 * (size_t)NN * FD;        // [0]=kl_sum, [1]=loss_sum
    float* agg_buf = h_buf;                         // alias: h dead after enc2
    float* out   = (float*)d_out;

    hipMemsetAsync(d_out, 0, (size_t)out_size * sizeof(float), stream);
    hipMemsetAsync(accum, 0, 2 * sizeof(float), stream);

    const int nblk = NN / TN;  // 15625
    enc1_kernel<<<nblk, 128, 0, stream>>>(op_id, sv_id, st_id, lat, opE, svE, stE, W1, b1, h_buf);
    enc2_kernel<<<nblk, 256, 0, stream>>>(h_buf, W2, b2, eps, z_buf, accum + 0);
    hipMemsetAsync(agg_buf, 0, (size_t)NN * FD * sizeof(float), stream);  // stream-ordered after enc2
    scatter_kernel<<<(NE * 32) / 256, 256, 0, stream>>>(esrc, edst, z_buf, agg_buf);
    dec_kernel<<<nblk, 128, 0, stream>>>(z_buf, agg_buf, Wself, Wagg, muW, mub, lvW, lvb,
                                         opwise, op_id, lat,
                                         out + 1, out + 1 + OPC, accum + 1);
    final_kernel<<<1, 1, 0, stream>>>(accum, out);
}

// Round 2
// 2675.250 us; speedup vs baseline: 1.7733x; 1.7733x over previous
//
#include <hip/hip_runtime.h>
#include <math.h>

#define NN 500000
#define NE 1000000
#define FD 128
#define OPC 5000
#define TN 32
#define NBLK_SCAN 489   // ceil(500000/1024)

// ---------------- enc1: h = relu(feats @ W1 + b1), k-split x 2-col ----------------
__global__ __launch_bounds__(128) void enc1_kernel(
    const int* __restrict__ op_id, const int* __restrict__ sv_id, const int* __restrict__ st_id,
    const float* __restrict__ lat,
    const float* __restrict__ opE, const float* __restrict__ svE, const float* __restrict__ stE,
    const float* __restrict__ W1, const float* __restrict__ b1,
    float* __restrict__ h)
{
    __shared__ float smem[8192];      // feats (6400 floats), later psum[2][32][128]
    __shared__ int ids[3 * TN];
    const int tid = threadIdx.x;
    const int base = blockIdx.x * TN;

    if (tid < TN) {
        int n = base + tid;
        ids[tid]          = op_id[n];
        ids[TN + tid]     = sv_id[n];
        ids[2 * TN + tid] = st_id[n];
    }
    __syncthreads();

    float4* feats4 = (float4*)smem;
    const float4* opE4 = (const float4*)opE;
    const float4* svE4 = (const float4*)svE;
    const float4* stE4 = (const float4*)stE;
    const float4* lat4 = (const float4*)lat;

    for (int idx = tid; idx < TN * 50; idx += 128) {
        int t = idx / 50, j = idx % 50;
        float4 v;
        if (j < 16)      v = opE4[(size_t)ids[t] * 16 + j];
        else if (j < 32) v = svE4[(size_t)ids[TN + t] * 16 + (j - 16)];
        else if (j < 48) v = stE4[(size_t)ids[2 * TN + t] * 16 + (j - 32)];
        else             v = lat4[(size_t)(base + t) * 2 + (j - 48)];
        feats4[t * 50 + j] = v;
    }
    __syncthreads();

    const int g  = tid >> 6;          // 0: k4 in [0,25), 1: [25,50)
    const int c0 = tid & 63, c1 = c0 + 64;
    const int k4lo = g ? 25 : 0;
    const int k4hi = g ? 50 : 25;

    float acc0[TN], acc1[TN];
    {
        float b0 = g ? 0.0f : b1[c0];
        float b1v = g ? 0.0f : b1[c1];
        #pragma unroll
        for (int t = 0; t < TN; t++) { acc0[t] = b0; acc1[t] = b1v; }
    }
    for (int k4 = k4lo; k4 < k4hi; k4++) {
        const float* wp = W1 + (size_t)k4 * 4 * FD;
        float w00 = wp[c0], w01 = wp[FD + c0], w02 = wp[2 * FD + c0], w03 = wp[3 * FD + c0];
        float w10 = wp[c1], w11 = wp[FD + c1], w12 = wp[2 * FD + c1], w13 = wp[3 * FD + c1];
        #pragma unroll
        for (int t = 0; t < TN; t++) {
            float4 v = feats4[t * 50 + k4];
            acc0[t] = fmaf(v.x, w00, acc0[t]);
            acc0[t] = fmaf(v.y, w01, acc0[t]);
            acc0[t] = fmaf(v.z, w02, acc0[t]);
            acc0[t] = fmaf(v.w, w03, acc0[t]);
            acc1[t] = fmaf(v.x, w10, acc1[t]);
            acc1[t] = fmaf(v.y, w11, acc1[t]);
            acc1[t] = fmaf(v.z, w12, acc1[t]);
            acc1[t] = fmaf(v.w, w13, acc1[t]);
        }
    }
    __syncthreads();   // feats dead
    #pragma unroll
    for (int t = 0; t < TN; t++) {
        smem[g * 4096 + t * 128 + c0] = acc0[t];
        smem[g * 4096 + t * 128 + c1] = acc1[t];
    }
    __syncthreads();
    #pragma unroll
    for (int t = 0; t < TN; t++) {
        float v = smem[t * 128 + tid] + smem[4096 + t * 128 + tid];
        h[(size_t)(base + t) * FD + tid] = fmaxf(v, 0.0f);
    }
}

// ---------------- enc2: mu/lv col-pair per thread; z + KL fused, no LDS exchange --------
__global__ __launch_bounds__(128) void enc2_kernel(
    const float* __restrict__ h, const float* __restrict__ W2, const float* __restrict__ b2,
    const float* __restrict__ eps, float* __restrict__ z, float* __restrict__ kl_sum)
{
    __shared__ float4 ht4[TN * 32];   // 16 KB
    const int tid = threadIdx.x;
    const int base = blockIdx.x * TN;

    const float4* h4 = (const float4*)h;
    for (int idx = tid; idx < TN * 32; idx += 128)
        ht4[idx] = h4[(size_t)base * 32 + idx];
    __syncthreads();

    const int f = tid, f2 = tid + 128;
    float am[TN], al[TN];
    {
        float bm = b2[f], bl = b2[f2];
        #pragma unroll
        for (int t = 0; t < TN; t++) { am[t] = bm; al[t] = bl; }
    }
    for (int k4 = 0; k4 < 32; k4++) {
        const float* wp = W2 + (size_t)k4 * 4 * 256;
        float m0 = wp[f],        m1 = wp[256 + f],  m2 = wp[512 + f],  m3 = wp[768 + f];
        float l0 = wp[f2],       l1 = wp[256 + f2], l2 = wp[512 + f2], l3 = wp[768 + f2];
        #pragma unroll
        for (int t = 0; t < TN; t++) {
            float4 v = ht4[t * 32 + k4];
            am[t] = fmaf(v.x, m0, am[t]);
            am[t] = fmaf(v.y, m1, am[t]);
            am[t] = fmaf(v.z, m2, am[t]);
            am[t] = fmaf(v.w, m3, am[t]);
            al[t] = fmaf(v.x, l0, al[t]);
            al[t] = fmaf(v.y, l1, al[t]);
            al[t] = fmaf(v.z, l2, al[t]);
            al[t] = fmaf(v.w, l3, al[t]);
        }
    }

    float kll = 0.0f;
    #pragma unroll
    for (int t = 0; t < TN; t++) {
        float lv = tanhf(al[t]);
        float mu = am[t];
        float e  = eps[(size_t)(base + t) * FD + f];
        z[(size_t)(base + t) * FD + f] = mu + expf(0.5f * lv) * e;
        kll += lv + 1.0f - expf(lv) - mu * mu;
    }
    #pragma unroll
    for (int off = 32; off > 0; off >>= 1) kll += __shfl_down(kll, off);
    if ((tid & 63) == 0) atomicAdd(kl_sum, kll);
}

// ---------------- CSR build ----------------
__global__ void hist_kernel(const int* __restrict__ edst, int* __restrict__ cnt)
{
    int e = blockIdx.x * 256 + threadIdx.x;
    if (e < NE) atomicAdd(&cnt[edst[e]], 1);
}

__global__ void scan1_kernel(const int* __restrict__ cnt, int* __restrict__ bsum)
{
    __shared__ int ls[256];
    int b = blockIdx.x, tid = threadIdx.x;
    int idx0 = b * 1024 + tid * 4;
    int s = 0;
    #pragma unroll
    for (int i = 0; i < 4; i++) { int idx = idx0 + i; if (idx < NN) s += cnt[idx]; }
    ls[tid] = s; __syncthreads();
    for (int off = 128; off > 0; off >>= 1) {
        if (tid < off) ls[tid] += ls[tid + off];
        __syncthreads();
    }
    if (tid == 0) bsum[b] = ls[0];
}

__global__ void scan2_kernel(int* __restrict__ bsum, int* __restrict__ rowstart)
{
    __shared__ int ls[512];
    int tid = threadIdx.x;
    int v = (tid < NBLK_SCAN) ? bsum[tid] : 0;
    ls[tid] = v; __syncthreads();
    for (int off = 1; off < 512; off <<= 1) {
        int t = 0;
        if (tid >= off) t = ls[tid - off];
        __syncthreads();
        ls[tid] += t;
        __syncthreads();
    }
    if (tid < NBLK_SCAN) bsum[tid] = (tid == 0) ? 0 : ls[tid - 1];
    if (tid == 0) rowstart[NN] = NE;
}

__global__ void scan3_kernel(const int* __restrict__ cnt, const int* __restrict__ bsum,
                             int* __restrict__ rowstart, int* __restrict__ cursor)
{
    __shared__ int ls[256];
    int b = blockIdx.x, tid = threadIdx.x;
    int idx0 = b * 1024 + tid * 4;
    int v[4]; int s = 0;
    #pragma unroll
    for (int i = 0; i < 4; i++) { int idx = idx0 + i; v[i] = (idx < NN) ? cnt[idx] : 0; s += v[i]; }
    ls[tid] = s; __syncthreads();
    for (int off = 1; off < 256; off <<= 1) {
        int t = 0;
        if (tid >= off) t = ls[tid - off];
        __syncthreads();
        ls[tid] += t;
        __syncthreads();
    }
    int ex = ls[tid] - s + bsum[b];
    #pragma unroll
    for (int i = 0; i < 4; i++) {
        int idx = idx0 + i;
        if (idx < NN) { rowstart[idx] = ex; cursor[idx] = ex; }
        ex += v[i];
    }
}

__global__ void fill_kernel(const int* __restrict__ esrc, const int* __restrict__ edst,
                            int* __restrict__ cursor, int* __restrict__ csr)
{
    int e = blockIdx.x * 256 + threadIdx.x;
    if (e < NE) {
        int pos = atomicAdd(&cursor[edst[e]], 1);
        csr[pos] = esrc[e];
    }
}

// ---------------- dec: fused CSR-gather + dual GEMM (operand split) + heads + loss ------
__global__ __launch_bounds__(128) void dec_kernel(
    const float* __restrict__ z, const int* __restrict__ rowstart, const int* __restrict__ csr,
    const float* __restrict__ Wself, const float* __restrict__ Wagg,
    const float* __restrict__ muW, const float* __restrict__ mub,
    const float* __restrict__ lvW, const float* __restrict__ lvb,
    const float* __restrict__ opwise, const int* __restrict__ op_id,
    const float* __restrict__ lat,
    float* __restrict__ op_loss, float* __restrict__ op_cnt,
    float* __restrict__ loss_sum)
{
    __shared__ float smem[8192];     // zt4|at4 (32 KB), later psum[2][32][128]
    __shared__ float ydl[TN * 129];
    __shared__ float mul_s[TN * 8], lvl_s[TN * 8];

    const int tid = threadIdx.x;
    const int base = blockIdx.x * TN;

    float4* zt4 = (float4*)smem;              // 1024 float4
    float4* at4 = ((float4*)smem) + 1024;     // 1024 float4
    const float4* z4 = (const float4*)z;

    for (int idx = tid; idx < TN * 32; idx += 128)
        zt4[idx] = z4[(size_t)base * 32 + idx];

    // gather agg tile from CSR: 4 threads per node
    {
        int tg = tid >> 2, j = tid & 3;
        int n = base + tg;
        int r0 = rowstart[n], r1 = rowstart[n + 1];
        float4 a[8];
        #pragma unroll
        for (int i = 0; i < 8; i++) a[i] = make_float4(0.f, 0.f, 0.f, 0.f);
        for (int e = r0; e < r1; e++) {
            const float4* zp = z4 + (size_t)csr[e] * 32;
            #pragma unroll
            for (int i = 0; i < 8; i++) {
                float4 v = zp[i * 4 + j];
                a[i].x += v.x; a[i].y += v.y; a[i].z += v.z; a[i].w += v.w;
            }
        }
        #pragma unroll
        for (int i = 0; i < 8; i++) at4[tg * 32 + i * 4 + j] = a[i];
    }
    __syncthreads();

    const int g  = tid >> 6;                  // 0: self-GEMM, 1: agg-GEMM
    const int c0 = tid & 63, c1 = c0 + 64;
    const float*  W = g ? Wagg : Wself;
    const float4* X = g ? at4 : zt4;

    float acc0[TN], acc1[TN];
    #pragma unroll
    for (int t = 0; t < TN; t++) { acc0[t] = 0.0f; acc1[t] = 0.0f; }
    for (int k4 = 0; k4 < 32; k4++) {
        const float* wp = W + (size_t)k4 * 4 * FD;
        float w00 = wp[c0], w01 = wp[FD + c0], w02 = wp[2 * FD + c0], w03 = wp[3 * FD + c0];
        float w10 = wp[c1], w11 = wp[FD + c1], w12 = wp[2 * FD + c1], w13 = wp[3 * FD + c1];
        #pragma unroll
        for (int t = 0; t < TN; t++) {
            float4 v = X[t * 32 + k4];
            acc0[t] = fmaf(v.x, w00, acc0[t]);
            acc0[t] = fmaf(v.y, w01, acc0[t]);
            acc0[t] = fmaf(v.z, w02, acc0[t]);
            acc0[t] = fmaf(v.w, w03, acc0[t]);
            acc1[t] = fmaf(v.x, w10, acc1[t]);
            acc1[t] = fmaf(v.y, w11, acc1[t]);
            acc1[t] = fmaf(v.z, w12, acc1[t]);
            acc1[t] = fmaf(v.w, w13, acc1[t]);
        }
    }
    __syncthreads();  // zt4/at4 dead
    #pragma unroll
    for (int t = 0; t < TN; t++) {
        smem[g * 4096 + t * 128 + c0] = acc0[t];
        smem[g * 4096 + t * 128 + c1] = acc1[t];
    }
    __syncthreads();
    #pragma unroll
    for (int t = 0; t < TN; t++)
        ydl[t * 129 + tid] = fmaxf(smem[t * 128 + tid] + smem[4096 + t * 128 + tid], 0.0f);
    __syncthreads();

    // mu/lv heads
    for (int half = 0; half < 2; half++) {
        int th = half * 16 + (tid >> 3);
        int l = tid & 7;
        float ma = mub[l], la = lvb[l];
        for (int k = 0; k < FD; k++) {
            float yv = ydl[th * 129 + k];
            ma = fmaf(yv, muW[k * 8 + l], ma);
            la = fmaf(yv, lvW[k * 8 + l], la);
        }
        mul_s[th * 8 + l] = ma;
        lvl_s[th * 8 + l] = la;
    }
    __syncthreads();

    float lsum = 0.0f;
    if (tid < TN) {
        int t = tid;
        int n = base + t;
        int op = op_id[n];
        const float4* w4 = (const float4*)(opwise + (size_t)op * 128);
        float mout[8], lout[8];
        #pragma unroll
        for (int k = 0; k < 8; k++) { mout[k] = 0.0f; lout[k] = 0.0f; }
        #pragma unroll
        for (int l = 0; l < 8; l++) {
            float m = mul_s[t * 8 + l];
            float v = lvl_s[t * 8 + l];
            float4 a = w4[l * 4 + 0];
            float4 b = w4[l * 4 + 1];
            float4 c = w4[l * 4 + 2];
            float4 d = w4[l * 4 + 3];
            mout[0] = fmaf(m, a.x, mout[0]); mout[1] = fmaf(m, a.y, mout[1]);
            mout[2] = fmaf(m, a.z, mout[2]); mout[3] = fmaf(m, a.w, mout[3]);
            mout[4] = fmaf(m, b.x, mout[4]); mout[5] = fmaf(m, b.y, mout[5]);
            mout[6] = fmaf(m, b.z, mout[6]); mout[7] = fmaf(m, b.w, mout[7]);
            lout[0] = fmaf(v, c.x, lout[0]); lout[1] = fmaf(v, c.y, lout[1]);
            lout[2] = fmaf(v, c.z, lout[2]); lout[3] = fmaf(v, c.w, lout[3]);
            lout[4] = fmaf(v, d.x, lout[4]); lout[5] = fmaf(v, d.y, lout[5]);
            lout[6] = fmaf(v, d.z, lout[6]); lout[7] = fmaf(v, d.w, lout[7]);
        }
        float lnode = 0.0f;
        #pragma unroll
        for (int k = 0; k < 8; k++) {
            float label = lat[(size_t)n * 8 + k];
            float diff  = mout[k] - label;
            lnode += diff * diff / (2.0f * expf(lout[k]) + 1e-7f) + 0.5f * lout[k];
        }
        lnode *= 0.125f;
        atomicAdd(&op_loss[op], lnode);
        atomicAdd(&op_cnt[op], 1.0f);
        lsum = lnode;
    }
    #pragma unroll
    for (int off = 32; off > 0; off >>= 1) lsum += __shfl_down(lsum, off);
    if ((tid & 63) == 0) atomicAdd(loss_sum, lsum);
}

// ---------------- finalize ----------------
__global__ void final_kernel(const float* __restrict__ accum, float* __restrict__ out)
{
    out[0] = accum[1] / (float)NN - 0.5f * (accum[0] / (float)((size_t)NN * 128));
}

extern "C" void kernel_launch(void* const* d_in, const int* in_sizes, int n_in,
                              void* d_out, int out_size, void* d_ws, size_t ws_size,
                              hipStream_t stream) {
    const int*   op_id  = (const int*)  d_in[0];
    const int*   sv_id  = (const int*)  d_in[1];
    const int*   st_id  = (const int*)  d_in[2];
    const float* lat    = (const float*)d_in[3];
    const int*   esrc   = (const int*)  d_in[4];
    const int*   edst   = (const int*)  d_in[5];
    const float* eps    = (const float*)d_in[6];
    const float* opE    = (const float*)d_in[7];
    const float* svE    = (const float*)d_in[8];
    const float* stE    = (const float*)d_in[9];
    const float* W1     = (const float*)d_in[10];
    const float* b1     = (const float*)d_in[11];
    const float* W2     = (const float*)d_in[12];
    const float* b2     = (const float*)d_in[13];
    const float* Wself  = (const float*)d_in[14];
    const float* Wagg   = (const float*)d_in[15];
    const float* muW    = (const float*)d_in[16];
    const float* mub    = (const float*)d_in[17];
    const float* lvW    = (const float*)d_in[18];
    const float* lvb    = (const float*)d_in[19];
    const float* opwise = (const float*)d_in[20];

    float* ws    = (float*)d_ws;
    float* h_buf = ws;                              // N*128 floats; CSR reuses this after enc2
    float* z_buf = ws + (size_t)NN * FD;            // N*128 floats
    float* accum = ws + 2 * (size_t)NN * FD;        // [0]=kl_sum, [1]=loss_sum
    float* out   = (float*)d_out;

    // CSR arrays aliased into h region (h is dead after enc2; stream order guarantees safety)
    int* cnt      = (int*)h_buf;                    // NN
    int* rowstart = cnt + 524288;                   // NN+1
    int* cursor   = rowstart + 524288;              // NN
    int* csr      = cursor + 524288;                // NE
    int* bsum     = csr + 1048576 + 64;             // NBLK_SCAN

    hipMemsetAsync(d_out, 0, (size_t)out_size * sizeof(float), stream);
    hipMemsetAsync(accum, 0, 2 * sizeof(float), stream);

    const int nblk = NN / TN;  // 15625
    enc1_kernel<<<nblk, 128, 0, stream>>>(op_id, sv_id, st_id, lat, opE, svE, stE, W1, b1, h_buf);
    enc2_kernel<<<nblk, 128, 0, stream>>>(h_buf, W2, b2, eps, z_buf, accum + 0);

    // CSR build (h region is now free)
    hipMemsetAsync(cnt, 0, (size_t)NN * sizeof(int), stream);
    hist_kernel<<<(NE + 255) / 256, 256, 0, stream>>>(edst, cnt);
    scan1_kernel<<<NBLK_SCAN, 256, 0, stream>>>(cnt, bsum);
    scan2_kernel<<<1, 512, 0, stream>>>(bsum, rowstart);
    scan3_kernel<<<NBLK_SCAN, 256, 0, stream>>>(cnt, bsum, rowstart, cursor);
    fill_kernel<<<(NE + 255) / 256, 256, 0, stream>>>(esrc, edst, cursor, csr);

    dec_kernel<<<nblk, 128, 0, stream>>>(z_buf, rowstart, csr, Wself, Wagg, muW, mub, lvW, lvb,
                                         opwise, op_id, lat,
                                         out + 1, out + 1 + OPC, accum + 1);
    final_kernel<<<1, 1, 0, stream>>>(accum, out);
}

// Round 3
// 1624.647 us; speedup vs baseline: 2.9201x; 1.6467x over previous
//
#include <hip/hip_runtime.h>
#include <math.h>

#define NN 500000
#define NE 1000000
#define OPC 5000
#define NBLK_SCAN 489   // ceil(500000/1024)

typedef short short8 __attribute__((ext_vector_type(8)));
typedef float f32x4 __attribute__((ext_vector_type(4)));

static __device__ __forceinline__ short f2bf(float f) {
    unsigned u = __builtin_bit_cast(unsigned, f);
    u += 0x7fffu + ((u >> 16) & 1u);
    return (short)(u >> 16);
}
static __device__ __forceinline__ float bf2f(short s) {
    unsigned u = ((unsigned)(unsigned short)s) << 16;
    return __builtin_bit_cast(float, u);
}

// ---------------- prep: weights -> bf16, [n][k] layout, padded ----------------
// W1p: [128 n][224 k] (k>=200 zero);  W2p: [256 n][128 k];  Wdp: [128 n][256 k] = [Wself;Wagg]
__global__ void prep_kernel(const float* __restrict__ W1, const float* __restrict__ W2,
                            const float* __restrict__ Wself, const float* __restrict__ Wagg,
                            short* __restrict__ W1p, short* __restrict__ W2p, short* __restrict__ Wdp)
{
    int idx = blockIdx.x * 256 + threadIdx.x;
    if (idx < 128 * 224) {
        int n = idx / 224, k = idx % 224;
        W1p[idx] = (k < 200) ? f2bf(W1[k * 128 + n]) : (short)0;
    }
    if (idx < 256 * 128) {
        int n = idx / 128, k = idx % 128;
        W2p[idx] = f2bf(W2[k * 256 + n]);
    }
    if (idx < 128 * 256) {
        int n = idx / 256, k = idx % 256;
        Wdp[idx] = (k < 128) ? f2bf(Wself[k * 128 + n]) : f2bf(Wagg[(k - 128) * 128 + n]);
    }
}

// A-fragment feat loader for enc1: k-chunk of 8 lies entirely in one segment
static __device__ __forceinline__ short8 load_feat(
    int kl, int op, int sv, int st, int node,
    const float* __restrict__ opE, const float* __restrict__ svE,
    const float* __restrict__ stE, const float* __restrict__ lat)
{
    short8 r;
    if (kl < 200) {
        const float* p;
        if (kl < 64)       p = opE + (size_t)op * 64 + kl;
        else if (kl < 128) p = svE + (size_t)sv * 64 + (kl - 64);
        else if (kl < 192) p = stE + (size_t)st * 64 + (kl - 128);
        else               p = lat + (size_t)node * 8;     // kl == 192
        float4 v0 = ((const float4*)p)[0];
        float4 v1 = ((const float4*)p)[1];
        r[0] = f2bf(v0.x); r[1] = f2bf(v0.y); r[2] = f2bf(v0.z); r[3] = f2bf(v0.w);
        r[4] = f2bf(v1.x); r[5] = f2bf(v1.y); r[6] = f2bf(v1.z); r[7] = f2bf(v1.w);
    } else {
        #pragma unroll
        for (int i = 0; i < 8; i++) r[i] = 0;
    }
    return r;
}

// ---------------- enc1: h = relu(feats @ W1 + b1), MFMA, 32 nodes/wave ----------------
__global__ __launch_bounds__(64) void enc1_mfma(
    const int* __restrict__ op_id, const int* __restrict__ sv_id, const int* __restrict__ st_id,
    const float* __restrict__ lat,
    const float* __restrict__ opE, const float* __restrict__ svE, const float* __restrict__ stE,
    const short* __restrict__ W1p, const float* __restrict__ b1,
    short* __restrict__ h_bf)
{
    const int lane = threadIdx.x;
    const int m = lane & 15, quad = lane >> 4;
    const int base = blockIdx.x * 32;
    const int n0 = base + m, n1 = base + 16 + m;
    const int op0 = op_id[n0], sv0 = sv_id[n0], st0 = st_id[n0];
    const int op1 = op_id[n1], sv1 = sv_id[n1], st1 = st_id[n1];

    f32x4 acc[2][8];
    #pragma unroll
    for (int a2 = 0; a2 < 2; a2++)
        #pragma unroll
        for (int nf = 0; nf < 8; nf++) acc[a2][nf] = (f32x4)0.0f;

    for (int s = 0; s < 7; s++) {
        const int kl = s * 32 + quad * 8;
        short8 a0 = load_feat(kl, op0, sv0, st0, n0, opE, svE, stE, lat);
        short8 a1 = load_feat(kl, op1, sv1, st1, n1, opE, svE, stE, lat);
        #pragma unroll
        for (int nf = 0; nf < 8; nf++) {
            short8 b = *(const short8*)(W1p + (nf * 16 + m) * 224 + kl);
            acc[0][nf] = __builtin_amdgcn_mfma_f32_16x16x32_bf16(a0, b, acc[0][nf], 0, 0, 0);
            acc[1][nf] = __builtin_amdgcn_mfma_f32_16x16x32_bf16(a1, b, acc[1][nf], 0, 0, 0);
        }
    }
    #pragma unroll
    for (int a2 = 0; a2 < 2; a2++)
        #pragma unroll
        for (int nf = 0; nf < 8; nf++) {
            int col = nf * 16 + m;
            float bb = b1[col];
            #pragma unroll
            for (int r = 0; r < 4; r++) {
                int node = base + a2 * 16 + quad * 4 + r;
                h_bf[(size_t)node * 128 + col] = f2bf(fmaxf(acc[a2][nf][r] + bb, 0.0f));
            }
        }
}

// ---------------- enc2: y = h@W2+b2; z=mu+exp(.5*tanh(lv))*eps; KL ----------------
__global__ __launch_bounds__(64) void enc2_mfma(
    const short* __restrict__ h_bf, const short* __restrict__ W2p, const float* __restrict__ b2,
    const float* __restrict__ eps, short* __restrict__ z_bf, float* __restrict__ kl_sum)
{
    const int lane = threadIdx.x;
    const int m = lane & 15, quad = lane >> 4;
    const int base = blockIdx.x * 32;

    f32x4 acc[2][16];
    #pragma unroll
    for (int a2 = 0; a2 < 2; a2++)
        #pragma unroll
        for (int nf = 0; nf < 16; nf++) acc[a2][nf] = (f32x4)0.0f;

    for (int s = 0; s < 4; s++) {
        const int kl = s * 32 + quad * 8;
        short8 a0 = *(const short8*)(h_bf + (size_t)(base + m) * 128 + kl);
        short8 a1 = *(const short8*)(h_bf + (size_t)(base + 16 + m) * 128 + kl);
        #pragma unroll
        for (int nf = 0; nf < 16; nf++) {
            short8 b = *(const short8*)(W2p + (nf * 16 + m) * 128 + kl);
            acc[0][nf] = __builtin_amdgcn_mfma_f32_16x16x32_bf16(a0, b, acc[0][nf], 0, 0, 0);
            acc[1][nf] = __builtin_amdgcn_mfma_f32_16x16x32_bf16(a1, b, acc[1][nf], 0, 0, 0);
        }
    }

    float kll = 0.0f;
    #pragma unroll
    for (int a2 = 0; a2 < 2; a2++)
        #pragma unroll
        for (int nf = 0; nf < 8; nf++) {
            int col = nf * 16 + m;
            float bm = b2[col], bl = b2[col + 128];
            #pragma unroll
            for (int r = 0; r < 4; r++) {
                int node = base + a2 * 16 + quad * 4 + r;
                float mu = acc[a2][nf][r] + bm;
                float lv = tanhf(acc[a2][nf + 8][r] + bl);
                float e  = eps[(size_t)node * 128 + col];
                z_bf[(size_t)node * 128 + col] = f2bf(mu + expf(0.5f * lv) * e);
                kll += lv + 1.0f - expf(lv) - mu * mu;
            }
        }
    #pragma unroll
    for (int off = 32; off > 0; off >>= 1) kll += __shfl_down(kll, off);
    if (lane == 0) atomicAdd(kl_sum, kll);
}

// ---------------- CSR build (unchanged from round 2) ----------------
__global__ void hist_kernel(const int* __restrict__ edst, int* __restrict__ cnt)
{
    int e = blockIdx.x * 256 + threadIdx.x;
    if (e < NE) atomicAdd(&cnt[edst[e]], 1);
}

__global__ void scan1_kernel(const int* __restrict__ cnt, int* __restrict__ bsum)
{
    __shared__ int ls[256];
    int b = blockIdx.x, tid = threadIdx.x;
    int idx0 = b * 1024 + tid * 4;
    int s = 0;
    #pragma unroll
    for (int i = 0; i < 4; i++) { int idx = idx0 + i; if (idx < NN) s += cnt[idx]; }
    ls[tid] = s; __syncthreads();
    for (int off = 128; off > 0; off >>= 1) {
        if (tid < off) ls[tid] += ls[tid + off];
        __syncthreads();
    }
    if (tid == 0) bsum[b] = ls[0];
}

__global__ void scan2_kernel(int* __restrict__ bsum, int* __restrict__ rowstart)
{
    __shared__ int ls[512];
    int tid = threadIdx.x;
    int v = (tid < NBLK_SCAN) ? bsum[tid] : 0;
    ls[tid] = v; __syncthreads();
    for (int off = 1; off < 512; off <<= 1) {
        int t = 0;
        if (tid >= off) t = ls[tid - off];
        __syncthreads();
        ls[tid] += t;
        __syncthreads();
    }
    if (tid < NBLK_SCAN) bsum[tid] = (tid == 0) ? 0 : ls[tid - 1];
    if (tid == 0) rowstart[NN] = NE;
}

__global__ void scan3_kernel(const int* __restrict__ cnt, const int* __restrict__ bsum,
                             int* __restrict__ rowstart, int* __restrict__ cursor)
{
    __shared__ int ls[256];
    int b = blockIdx.x, tid = threadIdx.x;
    int idx0 = b * 1024 + tid * 4;
    int v[4]; int s = 0;
    #pragma unroll
    for (int i = 0; i < 4; i++) { int idx = idx0 + i; v[i] = (idx < NN) ? cnt[idx] : 0; s += v[i]; }
    ls[tid] = s; __syncthreads();
    for (int off = 1; off < 256; off <<= 1) {
        int t = 0;
        if (tid >= off) t = ls[tid - off];
        __syncthreads();
        ls[tid] += t;
        __syncthreads();
    }
    int ex = ls[tid] - s + bsum[b];
    #pragma unroll
    for (int i = 0; i < 4; i++) {
        int idx = idx0 + i;
        if (idx < NN) { rowstart[idx] = ex; cursor[idx] = ex; }
        ex += v[i];
    }
}

__global__ void fill_kernel(const int* __restrict__ esrc, const int* __restrict__ edst,
                            int* __restrict__ cursor, int* __restrict__ csr)
{
    int e = blockIdx.x * 256 + threadIdx.x;
    if (e < NE) {
        int pos = atomicAdd(&cursor[edst[e]], 1);
        csr[pos] = esrc[e];
    }
}

// ---------------- gather: agg[n] = sum_{e in CSR[n]} z[src(e)], bf16 in/out ----------------
__global__ __launch_bounds__(256) void gather_kernel(
    const int* __restrict__ rowstart, const int* __restrict__ csr,
    const short* __restrict__ z_bf, short* __restrict__ agg_bf)
{
    const int tid = threadIdx.x;
    const int g = tid >> 4, j = tid & 15;
    const int n = blockIdx.x * 16 + g;
    const int r0 = rowstart[n], r1 = rowstart[n + 1];
    float a[8];
    #pragma unroll
    for (int i = 0; i < 8; i++) a[i] = 0.0f;
    for (int e = r0; e < r1; e++) {
        short8 v = *(const short8*)(z_bf + (size_t)csr[e] * 128 + j * 8);
        #pragma unroll
        for (int i = 0; i < 8; i++) a[i] += bf2f(v[i]);
    }
    short8 o;
    #pragma unroll
    for (int i = 0; i < 8; i++) o[i] = f2bf(a[i]);
    *(short8*)(agg_bf + (size_t)n * 128 + j * 8) = o;
}

// ---------------- dec: yd=relu([z|agg]@Wd) via MFMA; heads; loss; segment sums ----------------
__global__ __launch_bounds__(256) void dec_mfma(
    const short* __restrict__ z_bf, const short* __restrict__ agg_bf, const short* __restrict__ Wdp,
    const float* __restrict__ muW, const float* __restrict__ mub,
    const float* __restrict__ lvW, const float* __restrict__ lvb,
    const float* __restrict__ opwise, const int* __restrict__ op_id,
    const float* __restrict__ lat,
    float* __restrict__ op_loss, float* __restrict__ op_cnt,
    float* __restrict__ loss_sum)
{
    __shared__ float ydl[128 * 132];                 // 67.6 KB, stride 132 breaks head-read conflicts
    __shared__ float mul_s[128 * 8], lvl_s[128 * 8];

    const int tid = threadIdx.x;
    const int lane = tid & 63, w = tid >> 6;
    const int m = lane & 15, quad = lane >> 4;
    const int bbase = blockIdx.x * 128;
    const int wbase = bbase + w * 32;

    if (wbase < NN) {
        f32x4 acc[2][8];
        #pragma unroll
        for (int a2 = 0; a2 < 2; a2++)
            #pragma unroll
            for (int nf = 0; nf < 8; nf++) acc[a2][nf] = (f32x4)0.0f;

        for (int s = 0; s < 8; s++) {
            const int kl = (s & 3) * 32 + quad * 8;
            const short* src = (s < 4) ? z_bf : agg_bf;
            short8 a0 = *(const short8*)(src + (size_t)(wbase + m) * 128 + kl);
            short8 a1 = *(const short8*)(src + (size_t)(wbase + 16 + m) * 128 + kl);
            const int kfull = s * 32 + quad * 8;
            #pragma unroll
            for (int nf = 0; nf < 8; nf++) {
                short8 b = *(const short8*)(Wdp + (nf * 16 + m) * 256 + kfull);
                acc[0][nf] = __builtin_amdgcn_mfma_f32_16x16x32_bf16(a0, b, acc[0][nf], 0, 0, 0);
                acc[1][nf] = __builtin_amdgcn_mfma_f32_16x16x32_bf16(a1, b, acc[1][nf], 0, 0, 0);
            }
        }
        #pragma unroll
        for (int a2 = 0; a2 < 2; a2++)
            #pragma unroll
            for (int nf = 0; nf < 8; nf++)
                #pragma unroll
                for (int r = 0; r < 4; r++) {
                    int nl = w * 32 + a2 * 16 + quad * 4 + r;
                    ydl[nl * 132 + nf * 16 + m] = fmaxf(acc[a2][nf][r], 0.0f);
                }
    }
    __syncthreads();

    // heads: 128 nodes x 8 latent dims
    for (int idx = tid; idx < 128 * 8; idx += 256) {
        int nl = idx >> 3, l = idx & 7;
        if (bbase + nl < NN) {
            float ma = mub[l], la = lvb[l];
            const float* yrow = &ydl[nl * 132];
            for (int k = 0; k < 128; k++) {
                float yv = yrow[k];
                ma = fmaf(yv, muW[k * 8 + l], ma);
                la = fmaf(yv, lvW[k * 8 + l], la);
            }
            mul_s[idx] = ma; lvl_s[idx] = la;
        }
    }
    __syncthreads();

    float lsum = 0.0f;
    if (tid < 128 && bbase + tid < NN) {
        const int t = tid;
        const int n = bbase + t;
        const int op = op_id[n];
        const float4* w4 = (const float4*)(opwise + (size_t)op * 128);
        float mout[8], lout[8];
        #pragma unroll
        for (int k = 0; k < 8; k++) { mout[k] = 0.0f; lout[k] = 0.0f; }
        #pragma unroll
        for (int l = 0; l < 8; l++) {
            float mv = mul_s[t * 8 + l];
            float vv = lvl_s[t * 8 + l];
            float4 a = w4[l * 4 + 0];
            float4 b = w4[l * 4 + 1];
            float4 c = w4[l * 4 + 2];
            float4 d = w4[l * 4 + 3];
            mout[0] = fmaf(mv, a.x, mout[0]); mout[1] = fmaf(mv, a.y, mout[1]);
            mout[2] = fmaf(mv, a.z, mout[2]); mout[3] = fmaf(mv, a.w, mout[3]);
            mout[4] = fmaf(mv, b.x, mout[4]); mout[5] = fmaf(mv, b.y, mout[5]);
            mout[6] = fmaf(mv, b.z, mout[6]); mout[7] = fmaf(mv, b.w, mout[7]);
            lout[0] = fmaf(vv, c.x, lout[0]); lout[1] = fmaf(vv, c.y, lout[1]);
            lout[2] = fmaf(vv, c.z, lout[2]); lout[3] = fmaf(vv, c.w, lout[3]);
            lout[4] = fmaf(vv, d.x, lout[4]); lout[5] = fmaf(vv, d.y, lout[5]);
            lout[6] = fmaf(vv, d.z, lout[6]); lout[7] = fmaf(vv, d.w, lout[7]);
        }
        float lnode = 0.0f;
        #pragma unroll
        for (int k = 0; k < 8; k++) {
            float label = lat[(size_t)n * 8 + k];
            float diff  = mout[k] - label;
            lnode += diff * diff / (2.0f * expf(lout[k]) + 1e-7f) + 0.5f * lout[k];
        }
        lnode *= 0.125f;
        atomicAdd(&op_loss[op], lnode);
        atomicAdd(&op_cnt[op], 1.0f);
        lsum = lnode;
    }
    #pragma unroll
    for (int off = 32; off > 0; off >>= 1) lsum += __shfl_down(lsum, off);
    if ((tid & 63) == 0) atomicAdd(loss_sum, lsum);
}

// ---------------- finalize ----------------
__global__ void final_kernel(const float* __restrict__ accum, float* __restrict__ out)
{
    out[0] = accum[1] / (float)NN - 0.5f * (accum[0] / (float)((size_t)NN * 128));
}

extern "C" void kernel_launch(void* const* d_in, const int* in_sizes, int n_in,
                              void* d_out, int out_size, void* d_ws, size_t ws_size,
                              hipStream_t stream) {
    const int*   op_id  = (const int*)  d_in[0];
    const int*   sv_id  = (const int*)  d_in[1];
    const int*   st_id  = (const int*)  d_in[2];
    const float* lat    = (const float*)d_in[3];
    const int*   esrc   = (const int*)  d_in[4];
    const int*   edst   = (const int*)  d_in[5];
    const float* eps    = (const float*)d_in[6];
    const float* opE    = (const float*)d_in[7];
    const float* svE    = (const float*)d_in[8];
    const float* stE    = (const float*)d_in[9];
    const float* W1     = (const float*)d_in[10];
    const float* b1     = (const float*)d_in[11];
    const float* W2     = (const float*)d_in[12];
    const float* b2     = (const float*)d_in[13];
    const float* Wself  = (const float*)d_in[14];
    const float* Wagg   = (const float*)d_in[15];
    const float* muW    = (const float*)d_in[16];
    const float* mub    = (const float*)d_in[17];
    const float* lvW    = (const float*)d_in[18];
    const float* lvb    = (const float*)d_in[19];
    const float* opwise = (const float*)d_in[20];

    char* wsb = (char*)d_ws;
    short* W1p      = (short*)(wsb + 0);                    // 57344 B
    short* W2p      = (short*)(wsb + (64 << 10));           // 65536 B
    short* Wdp      = (short*)(wsb + (128 << 10));          // 65536 B
    float* accum    = (float*)(wsb + (192 << 10));          // 8 B: [0]=kl, [1]=loss
    int*   cnt      = (int*)  (wsb + (4  << 20));           // 2 MB
    int*   rowstart = (int*)  (wsb + (6  << 20));           // 2 MB + 4
    int*   cursor   = (int*)  (wsb + (9  << 20));           // 2 MB
    int*   csr      = (int*)  (wsb + (12 << 20));           // 4 MB
    int*   bsum     = (int*)  (wsb + (16 << 20));           // small
    short* h_bf     = (short*)(wsb + (32  << 20));          // 128 MB
    short* z_bf     = (short*)(wsb + (160ull << 20));       // 128 MB
    short* agg_bf   = (short*)(wsb + (288ull << 20));       // 128 MB
    float* out      = (float*)d_out;

    hipMemsetAsync(d_out, 0, (size_t)out_size * sizeof(float), stream);
    hipMemsetAsync(accum, 0, 2 * sizeof(float), stream);
    hipMemsetAsync(cnt, 0, (size_t)NN * sizeof(int), stream);

    prep_kernel<<<128, 256, 0, stream>>>(W1, W2, Wself, Wagg, W1p, W2p, Wdp);

    // CSR build
    hist_kernel<<<(NE + 255) / 256, 256, 0, stream>>>(edst, cnt);
    scan1_kernel<<<NBLK_SCAN, 256, 0, stream>>>(cnt, bsum);
    scan2_kernel<<<1, 512, 0, stream>>>(bsum, rowstart);
    scan3_kernel<<<NBLK_SCAN, 256, 0, stream>>>(cnt, bsum, rowstart, cursor);
    fill_kernel<<<(NE + 255) / 256, 256, 0, stream>>>(esrc, edst, cursor, csr);

    const int nwave = NN / 32;  // 15625
    enc1_mfma<<<nwave, 64, 0, stream>>>(op_id, sv_id, st_id, lat, opE, svE, stE, W1p, b1, h_bf);
    enc2_mfma<<<nwave, 64, 0, stream>>>(h_bf, W2p, b2, eps, z_bf, accum + 0);
    gather_kernel<<<NN / 16, 256, 0, stream>>>(rowstart, csr, z_bf, agg_bf);
    dec_mfma<<<(NN + 127) / 128, 256, 0, stream>>>(z_bf, agg_bf, Wdp, muW, mub, lvW, lvb,
                                                   opwise, op_id, lat,
                                                   out + 1, out + 1 + OPC, accum + 1);
    final_kernel<<<1, 1, 0, stream>>>(accum, out);
}

// Round 4
// 1324.906 us; speedup vs baseline: 3.5807x; 1.2262x over previous
//
#include <hip/hip_runtime.h>
#include <math.h>

#define NN 500000
#define NE 1000000
#define OPC 5000
#define NBLK_SCAN 489   // ceil(500000/1024)
#define NBLK ((NN + 127) / 128)   // 3907

typedef short short8 __attribute__((ext_vector_type(8)));
typedef float f32x4 __attribute__((ext_vector_type(4)));

static __device__ __forceinline__ short f2bf(float f) {
    unsigned u = __builtin_bit_cast(unsigned, f);
    u += 0x7fffu + ((u >> 16) & 1u);
    return (short)(u >> 16);
}
static __device__ __forceinline__ float bf2f(short s) {
    unsigned u = ((unsigned)(unsigned short)s) << 16;
    return __builtin_bit_cast(float, u);
}
static __device__ __forceinline__ short8 cvt8(float4 a, float4 b) {
    short8 r;
    r[0] = f2bf(a.x); r[1] = f2bf(a.y); r[2] = f2bf(a.z); r[3] = f2bf(a.w);
    r[4] = f2bf(b.x); r[5] = f2bf(b.y); r[6] = f2bf(b.z); r[7] = f2bf(b.w);
    return r;
}

// ---------------- prep: weights -> bf16 [n][k] ----------------
// W1p[128][224] (k>=200 zero), W2p[256][128], Wdp[128][256]=[Wself|Wagg], HWp[16][128]=[muW;lvW]
__global__ void prep_kernel(const float* __restrict__ W1, const float* __restrict__ W2,
                            const float* __restrict__ Wself, const float* __restrict__ Wagg,
                            const float* __restrict__ muW, const float* __restrict__ lvW,
                            short* __restrict__ W1p, short* __restrict__ W2p,
                            short* __restrict__ Wdp, short* __restrict__ HWp)
{
    int idx = blockIdx.x * 256 + threadIdx.x;
    if (idx < 128 * 224) {
        int n = idx / 224, k = idx % 224;
        W1p[idx] = (k < 200) ? f2bf(W1[k * 128 + n]) : (short)0;
    }
    if (idx < 256 * 128) {
        int n = idx / 128, k = idx % 128;
        W2p[idx] = f2bf(W2[k * 256 + n]);
    }
    if (idx < 128 * 256) {
        int n = idx / 256, k = idx % 256;
        Wdp[idx] = (k < 128) ? f2bf(Wself[k * 128 + n]) : f2bf(Wagg[(k - 128) * 128 + n]);
    }
    if (idx < 16 * 128) {
        int n = idx / 128, k = idx % 128;
        HWp[idx] = (n < 8) ? f2bf(muW[k * 8 + n]) : f2bf(lvW[k * 8 + (n - 8)]);
    }
}

// ---------------- enc1: h = relu(feats @ W1 + b1), staged MFMA ----------------
__global__ __launch_bounds__(256) void enc1_mfma(
    const int* __restrict__ op_id, const int* __restrict__ sv_id, const int* __restrict__ st_id,
    const float* __restrict__ lat,
    const float* __restrict__ opE, const float* __restrict__ svE, const float* __restrict__ stE,
    const short* __restrict__ W1p, const float* __restrict__ b1,
    short* __restrict__ h_bf)
{
    __shared__ __align__(16) short Ab[128 * 40];
    __shared__ __align__(16) short Bb[128 * 40];
    __shared__ int ids_s[3 * 128];

    const int tid = threadIdx.x;
    const int lane = tid & 63, w = tid >> 6;
    const int m = lane & 15, q = lane >> 4;
    const int bbase = blockIdx.x * 128;
    const int wbase = bbase + w * 32;
    const bool wv = (wbase < NN);
    const int row = tid >> 1, hf = tid & 1;

    for (int i = tid; i < 128; i += 256) {
        int n = bbase + i;
        bool val = (n < NN);
        ids_s[i]       = val ? op_id[n] : 0;
        ids_s[128 + i] = val ? sv_id[n] : 0;
        ids_s[256 + i] = val ? st_id[n] : 0;
    }
    __syncthreads();

    f32x4 acc[2][8];
    #pragma unroll
    for (int a2 = 0; a2 < 2; a2++)
        #pragma unroll
        for (int nf = 0; nf < 8; nf++) acc[a2][nf] = (f32x4)0.0f;

    for (int s = 0; s < 7; s++) {
        // stage B: W1p cols 0..127, k-slice s*32..+31 (2 short8 per thread)
        {
            const short8* sp = (const short8*)(W1p + row * 224 + s * 32 + hf * 16);
            short8 v0 = sp[0], v1 = sp[1];
            *(short8*)&Bb[row * 40 + hf * 16]     = v0;
            *(short8*)&Bb[row * 40 + hf * 16 + 8] = v1;
        }
        // stage A: feats slice fp32 -> bf16 (each thread 16 floats)
        {
            short8 o0, o1;
            if (s < 6) {
                const float* basep;
                if (s < 2)      basep = opE + (size_t)ids_s[row] * 64;
                else if (s < 4) basep = svE + (size_t)ids_s[128 + row] * 64;
                else            basep = stE + (size_t)ids_s[256 + row] * 64;
                const float4* p = (const float4*)(basep + (s & 1) * 32 + hf * 16);
                float4 v0 = p[0], v1 = p[1], v2 = p[2], v3 = p[3];
                o0 = cvt8(v0, v1);
                o1 = cvt8(v2, v3);
            } else {
                #pragma unroll
                for (int i = 0; i < 8; i++) { o0[i] = 0; o1[i] = 0; }
                int n = bbase + row;
                if (hf == 0 && n < NN) {
                    const float4* p = (const float4*)(lat + (size_t)n * 8);
                    o0 = cvt8(p[0], p[1]);
                }
            }
            *(short8*)&Ab[row * 40 + hf * 16]     = o0;
            *(short8*)&Ab[row * 40 + hf * 16 + 8] = o1;
        }
        __syncthreads();
        if (wv) {
            const short8 a0 = *(const short8*)&Ab[(w * 32 + m) * 40 + q * 8];
            const short8 a1 = *(const short8*)&Ab[(w * 32 + 16 + m) * 40 + q * 8];
            #pragma unroll
            for (int nf = 0; nf < 8; nf++) {
                const short8 b = *(const short8*)&Bb[(nf * 16 + m) * 40 + q * 8];
                acc[0][nf] = __builtin_amdgcn_mfma_f32_16x16x32_bf16(a0, b, acc[0][nf], 0, 0, 0);
                acc[1][nf] = __builtin_amdgcn_mfma_f32_16x16x32_bf16(a1, b, acc[1][nf], 0, 0, 0);
            }
        }
        __syncthreads();
    }
    if (wv) {
        #pragma unroll
        for (int a2 = 0; a2 < 2; a2++)
            #pragma unroll
            for (int nf = 0; nf < 8; nf++) {
                int col = nf * 16 + m;
                float bb = b1[col];
                #pragma unroll
                for (int r = 0; r < 4; r++) {
                    int node = wbase + a2 * 16 + q * 4 + r;
                    h_bf[(size_t)node * 128 + col] = f2bf(fmaxf(acc[a2][nf][r] + bb, 0.0f));
                }
            }
    }
}

// ---------------- enc2: y=h@W2+b2; z=mu+exp(.5*tanh(lv))*eps; KL ----------------
__global__ __launch_bounds__(256) void enc2_mfma(
    const short* __restrict__ h_bf, const short* __restrict__ W2p, const float* __restrict__ b2,
    const float* __restrict__ eps, short* __restrict__ z_bf, float* __restrict__ kl_sum)
{
    __shared__ __align__(16) short Ab[128 * 40];
    __shared__ __align__(16) short Bb[256 * 40];

    const int tid = threadIdx.x;
    const int lane = tid & 63, w = tid >> 6;
    const int m = lane & 15, q = lane >> 4;
    const int bbase = blockIdx.x * 128;
    const int wbase = bbase + w * 32;
    const bool wv = (wbase < NN);
    const int row = tid >> 1, hf = tid & 1;

    f32x4 acc[2][16];
    #pragma unroll
    for (int a2 = 0; a2 < 2; a2++)
        #pragma unroll
        for (int nf = 0; nf < 16; nf++) acc[a2][nf] = (f32x4)0.0f;

    for (int s = 0; s < 4; s++) {
        // stage B: 256 cols, each thread one full col-slice (4 short8)
        {
            const short8* sp = (const short8*)(W2p + tid * 128 + s * 32);
            short8 v0 = sp[0], v1 = sp[1], v2 = sp[2], v3 = sp[3];
            *(short8*)&Bb[tid * 40 + 0]  = v0;
            *(short8*)&Bb[tid * 40 + 8]  = v1;
            *(short8*)&Bb[tid * 40 + 16] = v2;
            *(short8*)&Bb[tid * 40 + 24] = v3;
        }
        // stage A: h slice (bf16 copy)
        {
            const short8* sp = (const short8*)(h_bf + (size_t)(bbase + row) * 128 + s * 32 + hf * 16);
            short8 v0 = sp[0], v1 = sp[1];
            *(short8*)&Ab[row * 40 + hf * 16]     = v0;
            *(short8*)&Ab[row * 40 + hf * 16 + 8] = v1;
        }
        __syncthreads();
        if (wv) {
            const short8 a0 = *(const short8*)&Ab[(w * 32 + m) * 40 + q * 8];
            const short8 a1 = *(const short8*)&Ab[(w * 32 + 16 + m) * 40 + q * 8];
            #pragma unroll
            for (int nf = 0; nf < 16; nf++) {
                const short8 b = *(const short8*)&Bb[(nf * 16 + m) * 40 + q * 8];
                acc[0][nf] = __builtin_amdgcn_mfma_f32_16x16x32_bf16(a0, b, acc[0][nf], 0, 0, 0);
                acc[1][nf] = __builtin_amdgcn_mfma_f32_16x16x32_bf16(a1, b, acc[1][nf], 0, 0, 0);
            }
        }
        __syncthreads();
    }

    float kll = 0.0f;
    if (wv) {
        #pragma unroll
        for (int a2 = 0; a2 < 2; a2++)
            #pragma unroll
            for (int nf = 0; nf < 8; nf++) {
                int col = nf * 16 + m;
                float bm = b2[col], bl = b2[col + 128];
                #pragma unroll
                for (int r = 0; r < 4; r++) {
                    int node = wbase + a2 * 16 + q * 4 + r;
                    float mu = acc[a2][nf][r] + bm;
                    float lv = tanhf(acc[a2][nf + 8][r] + bl);
                    float e  = eps[(size_t)node * 128 + col];
                    z_bf[(size_t)node * 128 + col] = f2bf(mu + expf(0.5f * lv) * e);
                    kll += lv + 1.0f - expf(lv) - mu * mu;
                }
            }
    }
    #pragma unroll
    for (int off = 32; off > 0; off >>= 1) kll += __shfl_down(kll, off);
    if (lane == 0) atomicAdd(kl_sum, kll);
}

// ---------------- CSR build ----------------
__global__ void hist_kernel(const int* __restrict__ edst, int* __restrict__ cnt)
{
    int e = blockIdx.x * 256 + threadIdx.x;
    if (e < NE) atomicAdd(&cnt[edst[e]], 1);
}

__global__ void scan1_kernel(const int* __restrict__ cnt, int* __restrict__ bsum)
{
    __shared__ int ls[256];
    int b = blockIdx.x, tid = threadIdx.x;
    int idx0 = b * 1024 + tid * 4;
    int s = 0;
    #pragma unroll
    for (int i = 0; i < 4; i++) { int idx = idx0 + i; if (idx < NN) s += cnt[idx]; }
    ls[tid] = s; __syncthreads();
    for (int off = 128; off > 0; off >>= 1) {
        if (tid < off) ls[tid] += ls[tid + off];
        __syncthreads();
    }
    if (tid == 0) bsum[b] = ls[0];
}

__global__ void scan2_kernel(int* __restrict__ bsum, int* __restrict__ rowstart)
{
    __shared__ int ls[512];
    int tid = threadIdx.x;
    int v = (tid < NBLK_SCAN) ? bsum[tid] : 0;
    ls[tid] = v; __syncthreads();
    for (int off = 1; off < 512; off <<= 1) {
        int t = 0;
        if (tid >= off) t = ls[tid - off];
        __syncthreads();
        ls[tid] += t;
        __syncthreads();
    }
    if (tid < NBLK_SCAN) bsum[tid] = (tid == 0) ? 0 : ls[tid - 1];
    if (tid == 0) rowstart[NN] = NE;
}

__global__ void scan3_kernel(const int* __restrict__ cnt, const int* __restrict__ bsum,
                             int* __restrict__ rowstart, int* __restrict__ cursor)
{
    __shared__ int ls[256];
    int b = blockIdx.x, tid = threadIdx.x;
    int idx0 = b * 1024 + tid * 4;
    int v[4]; int s = 0;
    #pragma unroll
    for (int i = 0; i < 4; i++) { int idx = idx0 + i; v[i] = (idx < NN) ? cnt[idx] : 0; s += v[i]; }
    ls[tid] = s; __syncthreads();
    for (int off = 1; off < 256; off <<= 1) {
        int t = 0;
        if (tid >= off) t = ls[tid - off];
        __syncthreads();
        ls[tid] += t;
        __syncthreads();
    }
    int ex = ls[tid] - s + bsum[b];
    #pragma unroll
    for (int i = 0; i < 4; i++) {
        int idx = idx0 + i;
        if (idx < NN) { rowstart[idx] = ex; cursor[idx] = ex; }
        ex += v[i];
    }
}

__global__ void fill_kernel(const int* __restrict__ esrc, const int* __restrict__ edst,
                            int* __restrict__ cursor, int* __restrict__ csr)
{
    int e = blockIdx.x * 256 + threadIdx.x;
    if (e < NE) {
        int pos = atomicAdd(&cursor[edst[e]], 1);
        csr[pos] = esrc[e];
    }
}

// ---------------- dec: fused gather + dual GEMM + MFMA heads + loss ----------------
__global__ __launch_bounds__(256) void dec_mfma(
    const short* __restrict__ z_bf, const int* __restrict__ rowstart, const int* __restrict__ csr,
    const short* __restrict__ Wdp, const short* __restrict__ HWp,
    const float* __restrict__ mub, const float* __restrict__ lvb,
    const float* __restrict__ opwise, const int* __restrict__ op_id,
    const float* __restrict__ lat,
    float* __restrict__ op_loss, float* __restrict__ op_cnt,
    float* __restrict__ loss_sum)
{
    __shared__ __align__(16) char smem[59648];
    short* agg_s = (short*)smem;              // [128][136] bf16 agg, later yd
    short* Bb    = (short*)(smem + 34816);    // [128][40]
    short* hw_s  = (short*)(smem + 45056);    // [16][136]
    short* Ab    = (short*)(smem + 49408);    // [128][40]
    float* mlv   = (float*)(smem + 49408);    // [128][16] (aliases Ab; Ab dead after s=3)

    const int tid = threadIdx.x;
    const int lane = tid & 63, w = tid >> 6;
    const int m = lane & 15, q = lane >> 4;
    const int bbase = blockIdx.x * 128;
    const int wbase = bbase + w * 32;
    const bool wv = (wbase < NN);
    const int row = tid >> 1, hf = tid & 1;

    // stage head weights [16][136]
    {
        int nn = tid >> 4, c = tid & 15;
        *(short8*)&hw_s[nn * 136 + c * 8] = *(const short8*)(HWp + nn * 128 + c * 8);
    }
    // gather agg tile into LDS (2 threads per node, 64 cols each)
    {
        int nodeL = tid & 127, hh = tid >> 7;
        int n = bbase + nodeL;
        float a[64];
        #pragma unroll
        for (int i = 0; i < 64; i++) a[i] = 0.0f;
        if (n < NN) {
            int r0 = rowstart[n], r1 = rowstart[n + 1];
            for (int e = r0; e < r1; e++) {
                const short8* zp = (const short8*)(z_bf + (size_t)csr[e] * 128 + hh * 64);
                #pragma unroll
                for (int j = 0; j < 8; j++) {
                    short8 v = zp[j];
                    #pragma unroll
                    for (int i = 0; i < 8; i++) a[j * 8 + i] += bf2f(v[i]);
                }
            }
        }
        #pragma unroll
        for (int k = 0; k < 32; k++) {
            unsigned p = ((unsigned)(unsigned short)f2bf(a[2 * k])) |
                         (((unsigned)(unsigned short)f2bf(a[2 * k + 1])) << 16);
            *(int*)&agg_s[nodeL * 136 + hh * 64 + 2 * k] = p;
        }
    }
    __syncthreads();

    f32x4 acc[2][8];
    #pragma unroll
    for (int a2 = 0; a2 < 2; a2++)
        #pragma unroll
        for (int nf = 0; nf < 8; nf++) acc[a2][nf] = (f32x4)0.0f;

    for (int s = 0; s < 8; s++) {
        {
            const short8* sp = (const short8*)(Wdp + row * 256 + s * 32 + hf * 16);
            short8 v0 = sp[0], v1 = sp[1];
            *(short8*)&Bb[row * 40 + hf * 16]     = v0;
            *(short8*)&Bb[row * 40 + hf * 16 + 8] = v1;
        }
        if (s < 4) {
            const short8* sp = (const short8*)(z_bf + (size_t)(bbase + row) * 128 + s * 32 + hf * 16);
            short8 v0 = sp[0], v1 = sp[1];
            *(short8*)&Ab[row * 40 + hf * 16]     = v0;
            *(short8*)&Ab[row * 40 + hf * 16 + 8] = v1;
        }
        __syncthreads();
        if (wv) {
            short8 a0, a1;
            if (s < 4) {
                a0 = *(const short8*)&Ab[(w * 32 + m) * 40 + q * 8];
                a1 = *(const short8*)&Ab[(w * 32 + 16 + m) * 40 + q * 8];
            } else {
                a0 = *(const short8*)&agg_s[(w * 32 + m) * 136 + (s - 4) * 32 + q * 8];
                a1 = *(const short8*)&agg_s[(w * 32 + 16 + m) * 136 + (s - 4) * 32 + q * 8];
            }
            #pragma unroll
            for (int nf = 0; nf < 8; nf++) {
                const short8 b = *(const short8*)&Bb[(nf * 16 + m) * 40 + q * 8];
                acc[0][nf] = __builtin_amdgcn_mfma_f32_16x16x32_bf16(a0, b, acc[0][nf], 0, 0, 0);
                acc[1][nf] = __builtin_amdgcn_mfma_f32_16x16x32_bf16(a1, b, acc[1][nf], 0, 0, 0);
            }
        }
        __syncthreads();
    }

    // yd = relu(acc) -> reuse agg_s
    if (wv) {
        #pragma unroll
        for (int a2 = 0; a2 < 2; a2++)
            #pragma unroll
            for (int nf = 0; nf < 8; nf++)
                #pragma unroll
                for (int r = 0; r < 4; r++) {
                    int nodeL = w * 32 + a2 * 16 + q * 4 + r;
                    agg_s[nodeL * 136 + nf * 16 + m] = f2bf(fmaxf(acc[a2][nf][r], 0.0f));
                }
    }
    __syncthreads();

    // heads via MFMA: [mu|lv](128 nodes x 16) = yd(128x128) @ HW^T
    if (wv) {
        f32x4 h0 = (f32x4)0.0f, h1 = (f32x4)0.0f;
        #pragma unroll
        for (int s2 = 0; s2 < 4; s2++) {
            short8 a0 = *(const short8*)&agg_s[(w * 32 + m) * 136 + s2 * 32 + q * 8];
            short8 a1 = *(const short8*)&agg_s[(w * 32 + 16 + m) * 136 + s2 * 32 + q * 8];
            short8 b  = *(const short8*)&hw_s[m * 136 + s2 * 32 + q * 8];
            h0 = __builtin_amdgcn_mfma_f32_16x16x32_bf16(a0, b, h0, 0, 0, 0);
            h1 = __builtin_amdgcn_mfma_f32_16x16x32_bf16(a1, b, h1, 0, 0, 0);
        }
        float hb = (m < 8) ? mub[m] : lvb[m - 8];
        #pragma unroll
        for (int r = 0; r < 4; r++) {
            mlv[(w * 32 + q * 4 + r) * 16 + m]      = h0[r] + hb;
            mlv[(w * 32 + 16 + q * 4 + r) * 16 + m] = h1[r] + hb;
        }
    }
    __syncthreads();

    // per-node loss + segment sums
    float lsum = 0.0f;
    if (tid < 128 && bbase + tid < NN) {
        const int t = tid;
        const int n = bbase + t;
        const int op = op_id[n];
        const float4* w4 = (const float4*)(opwise + (size_t)op * 128);
        float mout[8], lout[8];
        #pragma unroll
        for (int k = 0; k < 8; k++) { mout[k] = 0.0f; lout[k] = 0.0f; }
        #pragma unroll
        for (int l = 0; l < 8; l++) {
            float mv = mlv[t * 16 + l];
            float vv = mlv[t * 16 + 8 + l];
            float4 a = w4[l * 4 + 0];
            float4 b = w4[l * 4 + 1];
            float4 c = w4[l * 4 + 2];
            float4 d = w4[l * 4 + 3];
            mout[0] = fmaf(mv, a.x, mout[0]); mout[1] = fmaf(mv, a.y, mout[1]);
            mout[2] = fmaf(mv, a.z, mout[2]); mout[3] = fmaf(mv, a.w, mout[3]);
            mout[4] = fmaf(mv, b.x, mout[4]); mout[5] = fmaf(mv, b.y, mout[5]);
            mout[6] = fmaf(mv, b.z, mout[6]); mout[7] = fmaf(mv, b.w, mout[7]);
            lout[0] = fmaf(vv, c.x, lout[0]); lout[1] = fmaf(vv, c.y, lout[1]);
            lout[2] = fmaf(vv, c.z, lout[2]); lout[3] = fmaf(vv, c.w, lout[3]);
            lout[4] = fmaf(vv, d.x, lout[4]); lout[5] = fmaf(vv, d.y, lout[5]);
            lout[6] = fmaf(vv, d.z, lout[6]); lout[7] = fmaf(vv, d.w, lout[7]);
        }
        const float4* lp = (const float4*)(lat + (size_t)n * 8);
        float4 lb0 = lp[0], lb1 = lp[1];
        float labels[8] = {lb0.x, lb0.y, lb0.z, lb0.w, lb1.x, lb1.y, lb1.z, lb1.w};
        float lnode = 0.0f;
        #pragma unroll
        for (int k = 0; k < 8; k++) {
            float diff = mout[k] - labels[k];
            lnode += diff * diff / (2.0f * expf(lout[k]) + 1e-7f) + 0.5f * lout[k];
        }
        lnode *= 0.125f;
        atomicAdd(&op_loss[op], lnode);
        atomicAdd(&op_cnt[op], 1.0f);
        lsum = lnode;
    }
    #pragma unroll
    for (int off = 32; off > 0; off >>= 1) lsum += __shfl_down(lsum, off);
    if (lane == 0) atomicAdd(loss_sum, lsum);
}

// ---------------- finalize ----------------
__global__ void final_kernel(const float* __restrict__ accum, float* __restrict__ out)
{
    out[0] = accum[1] / (float)NN - 0.5f * (accum[0] / (float)((size_t)NN * 128));
}

extern "C" void kernel_launch(void* const* d_in, const int* in_sizes, int n_in,
                              void* d_out, int out_size, void* d_ws, size_t ws_size,
                              hipStream_t stream) {
    const int*   op_id  = (const int*)  d_in[0];
    const int*   sv_id  = (const int*)  d_in[1];
    const int*   st_id  = (const int*)  d_in[2];
    const float* lat    = (const float*)d_in[3];
    const int*   esrc   = (const int*)  d_in[4];
    const int*   edst   = (const int*)  d_in[5];
    const float* eps    = (const float*)d_in[6];
    const float* opE    = (const float*)d_in[7];
    const float* svE    = (const float*)d_in[8];
    const float* stE    = (const float*)d_in[9];
    const float* W1     = (const float*)d_in[10];
    const float* b1     = (const float*)d_in[11];
    const float* W2     = (const float*)d_in[12];
    const float* b2     = (const float*)d_in[13];
    const float* Wself  = (const float*)d_in[14];
    const float* Wagg   = (const float*)d_in[15];
    const float* muW    = (const float*)d_in[16];
    const float* mub    = (const float*)d_in[17];
    const float* lvW    = (const float*)d_in[18];
    const float* lvb    = (const float*)d_in[19];
    const float* opwise = (const float*)d_in[20];

    char* wsb = (char*)d_ws;
    short* W1p      = (short*)(wsb + 0);                    // 57344 B
    short* W2p      = (short*)(wsb + (64 << 10));           // 65536 B
    short* Wdp      = (short*)(wsb + (128 << 10));          // 65536 B
    short* HWp      = (short*)(wsb + (192 << 10));          // 4096 B
    float* accum    = (float*)(wsb + (200 << 10));          // 8 B: [0]=kl, [1]=loss
    int*   cnt      = (int*)  (wsb + (4  << 20));           // 2 MB
    int*   rowstart = (int*)  (wsb + (6  << 20));           // 2 MB + 4
    int*   cursor   = (int*)  (wsb + (9  << 20));           // 2 MB
    int*   csr      = (int*)  (wsb + (12 << 20));           // 4 MB
    int*   bsum     = (int*)  (wsb + (16 << 20));           // small
    short* h_bf     = (short*)(wsb + (32  << 20));          // 128 MB
    short* z_bf     = (short*)(wsb + (160ull << 20));       // 128 MB
    float* out      = (float*)d_out;

    hipMemsetAsync(d_out, 0, (size_t)out_size * sizeof(float), stream);
    hipMemsetAsync(accum, 0, 2 * sizeof(float), stream);
    hipMemsetAsync(cnt, 0, (size_t)NN * sizeof(int), stream);

    prep_kernel<<<128, 256, 0, stream>>>(W1, W2, Wself, Wagg, muW, lvW, W1p, W2p, Wdp, HWp);

    // CSR build
    hist_kernel<<<(NE + 255) / 256, 256, 0, stream>>>(edst, cnt);
    scan1_kernel<<<NBLK_SCAN, 256, 0, stream>>>(cnt, bsum);
    scan2_kernel<<<1, 512, 0, stream>>>(bsum, rowstart);
    scan3_kernel<<<NBLK_SCAN, 256, 0, stream>>>(cnt, bsum, rowstart, cursor);
    fill_kernel<<<(NE + 255) / 256, 256, 0, stream>>>(esrc, edst, cursor, csr);

    enc1_mfma<<<NBLK, 256, 0, stream>>>(op_id, sv_id, st_id, lat, opE, svE, stE, W1p, b1, h_bf);
    enc2_mfma<<<NBLK, 256, 0, stream>>>(h_bf, W2p, b2, eps, z_bf, accum + 0);
    dec_mfma<<<NBLK, 256, 0, stream>>>(z_bf, rowstart, csr, Wdp, HWp, mub, lvb,
                                       opwise, op_id, lat,
                                       out + 1, out + 1 + OPC, accum + 1);
    final_kernel<<<1, 1, 0, stream>>>(accum, out);
}

// Round 5
// 1166.748 us; speedup vs baseline: 4.0660x; 1.1356x over previous
//
#include <hip/hip_runtime.h>
#include <math.h>

#define NN 500000
#define NE 1000000
#define OPC 5000
#define NBLK_SCAN 489
#define NBLK ((NN + 127) / 128)   // 3907

typedef short short8 __attribute__((ext_vector_type(8)));
typedef float f32x4 __attribute__((ext_vector_type(4)));

static __device__ __forceinline__ short f2bf(float f) {
    unsigned u = __builtin_bit_cast(unsigned, f);
    u += 0x7fffu + ((u >> 16) & 1u);
    return (short)(u >> 16);
}
static __device__ __forceinline__ float bf2f(short s) {
    unsigned u = ((unsigned)(unsigned short)s) << 16;
    return __builtin_bit_cast(float, u);
}
static __device__ __forceinline__ short8 cvt8(float4 a, float4 b) {
    short8 r;
    r[0] = f2bf(a.x); r[1] = f2bf(a.y); r[2] = f2bf(a.z); r[3] = f2bf(a.w);
    r[4] = f2bf(b.x); r[5] = f2bf(b.y); r[6] = f2bf(b.z); r[7] = f2bf(b.w);
    return r;
}
static __device__ __forceinline__ short8 ldcvt(const float* p) {
    const float4* p4 = (const float4*)p;
    return cvt8(p4[0], p4[1]);
}

// ---------------- prep: weights -> bf16, [col][k] rows, XOR-swizzled LDS images ----------
// Swizzle: LDS slot c' of column col holds k-chunk c = c' ^ (col & 7)  (chunks = 8 shorts = 16B)
// W1s: 128 cols x 256 shorts (k<200 valid, rest 0). W2s: 256 x 128. Wds0/1: 128 x 128 each.
// HWp: [16][128] plain = [muW; lvW] columns.
__global__ void prep_kernel(const float* __restrict__ W1, const float* __restrict__ W2,
                            const float* __restrict__ Wself, const float* __restrict__ Wagg,
                            const float* __restrict__ muW, const float* __restrict__ lvW,
                            short* __restrict__ W1s, short* __restrict__ W2s,
                            short* __restrict__ Wds0, short* __restrict__ Wds1,
                            short* __restrict__ HWp)
{
    int idx = blockIdx.x * 256 + threadIdx.x;   // up to 32768
    {   // W1s: idx = col*256 + c'*8 + j
        int col = idx >> 8, r = idx & 255;
        int k = ((r >> 3) ^ (col & 7)) * 8 + (r & 7);
        W1s[idx] = (k < 200) ? f2bf(W1[k * 128 + col]) : (short)0;
    }
    {   // W2s: idx = col*128 + c'*8 + j  (col 0..255)
        int col = idx >> 7, r = idx & 127;
        int k = ((r >> 3) ^ (col & 7)) * 8 + (r & 7);
        W2s[idx] = f2bf(W2[k * 256 + col]);
    }
    if (idx < 128 * 128) {  // Wds0/1
        int col = idx >> 7, r = idx & 127;
        int k = ((r >> 3) ^ (col & 7)) * 8 + (r & 7);
        Wds0[idx] = f2bf(Wself[k * 128 + col]);
        Wds1[idx] = f2bf(Wagg[k * 128 + col]);
    }
    if (idx < 16 * 128) {
        int n = idx >> 7, k = idx & 127;
        HWp[idx] = (n < 8) ? f2bf(muW[k * 8 + n]) : f2bf(lvW[k * 8 + (n - 8)]);
    }
}

// ---------------- enc1: h = relu(feats @ W1 + b1) ----------------
__global__ __launch_bounds__(256, 2) void enc1_mfma(
    const int* __restrict__ op_id, const int* __restrict__ sv_id, const int* __restrict__ st_id,
    const float* __restrict__ lat,
    const float* __restrict__ opE, const float* __restrict__ svE, const float* __restrict__ stE,
    const short* __restrict__ W1s, const float* __restrict__ b1,
    short* __restrict__ h_bf)
{
    __shared__ __align__(16) short Bb[128 * 256];   // 64 KB swizzled W1
    const int tid = threadIdx.x;
    const int lane = tid & 63, w = tid >> 6;
    const int m = lane & 15, q = lane >> 4;
    const int wbase = blockIdx.x * 128 + w * 32;

    {   // identity copy 64KB (pre-swizzled image)
        const short8* g = (const short8*)W1s;
        short8* l = (short8*)Bb;
        #pragma unroll
        for (int i = 0; i < 16; i++) l[tid + 256 * i] = g[tid + 256 * i];
    }
    __syncthreads();
    if (wbase >= NN) return;

    const int n0 = wbase + m, n1 = wbase + 16 + m;
    const size_t op0 = (size_t)op_id[n0] * 64, op1 = (size_t)op_id[n1] * 64;
    const size_t sv0 = (size_t)sv_id[n0] * 64, sv1 = (size_t)sv_id[n1] * 64;
    const size_t st0 = (size_t)st_id[n0] * 64, st1 = (size_t)st_id[n1] * 64;

    f32x4 acc[2][8];
    #pragma unroll
    for (int a2 = 0; a2 < 2; a2++)
        #pragma unroll
        for (int nf = 0; nf < 8; nf++) acc[a2][nf] = (f32x4)0.0f;

    #pragma unroll
    for (int s = 0; s < 7; s++) {
        short8 a0, a1;
        if (s < 2) {
            a0 = ldcvt(opE + op0 + s * 32 + q * 8);
            a1 = ldcvt(opE + op1 + s * 32 + q * 8);
        } else if (s < 4) {
            a0 = ldcvt(svE + sv0 + (s - 2) * 32 + q * 8);
            a1 = ldcvt(svE + sv1 + (s - 2) * 32 + q * 8);
        } else if (s < 6) {
            a0 = ldcvt(stE + st0 + (s - 4) * 32 + q * 8);
            a1 = ldcvt(stE + st1 + (s - 4) * 32 + q * 8);
        } else {
            if (q == 0) {
                a0 = ldcvt(lat + (size_t)n0 * 8);
                a1 = ldcvt(lat + (size_t)n1 * 8);
            } else {
                #pragma unroll
                for (int i = 0; i < 8; i++) { a0[i] = 0; a1[i] = 0; }
            }
        }
        const int slot = ((4 * s + q) ^ (m & 7)) * 8;
        #pragma unroll
        for (int nf = 0; nf < 8; nf++) {
            const short8 b = *(const short8*)&Bb[(nf * 16 + m) * 256 + slot];
            acc[0][nf] = __builtin_amdgcn_mfma_f32_16x16x32_bf16(a0, b, acc[0][nf], 0, 0, 0);
            acc[1][nf] = __builtin_amdgcn_mfma_f32_16x16x32_bf16(a1, b, acc[1][nf], 0, 0, 0);
        }
    }
    #pragma unroll
    for (int a2 = 0; a2 < 2; a2++)
        #pragma unroll
        for (int nf = 0; nf < 8; nf++) {
            int col = nf * 16 + m;
            float bb = b1[col];
            #pragma unroll
            for (int r = 0; r < 4; r++) {
                int node = wbase + a2 * 16 + q * 4 + r;
                h_bf[(size_t)node * 128 + col] = f2bf(fmaxf(acc[a2][nf][r] + bb, 0.0f));
            }
        }
}

// ---------------- enc2: y=h@W2+b2; z=mu+exp(.5*tanh(lv))*eps; KL ----------------
__global__ __launch_bounds__(256, 2) void enc2_mfma(
    const short* __restrict__ h_bf, const short* __restrict__ W2s, const float* __restrict__ b2,
    const float* __restrict__ eps, short* __restrict__ z_bf, float* __restrict__ kl_sum)
{
    __shared__ __align__(16) short Bb[256 * 128];   // 64 KB swizzled W2
    const int tid = threadIdx.x;
    const int lane = tid & 63, w = tid >> 6;
    const int m = lane & 15, q = lane >> 4;
    const int wbase = blockIdx.x * 128 + w * 32;

    {
        const short8* g = (const short8*)W2s;
        short8* l = (short8*)Bb;
        #pragma unroll
        for (int i = 0; i < 16; i++) l[tid + 256 * i] = g[tid + 256 * i];
    }
    __syncthreads();
    if (wbase >= NN) return;

    // upfront A fragments (2 row tiles x 4 k-steps)
    short8 a[2][4];
    #pragma unroll
    for (int s = 0; s < 4; s++) {
        a[0][s] = *(const short8*)(h_bf + (size_t)(wbase + m) * 128 + s * 32 + q * 8);
        a[1][s] = *(const short8*)(h_bf + (size_t)(wbase + 16 + m) * 128 + s * 32 + q * 8);
    }

    f32x4 acc[2][16];
    #pragma unroll
    for (int a2 = 0; a2 < 2; a2++)
        #pragma unroll
        for (int nf = 0; nf < 16; nf++) acc[a2][nf] = (f32x4)0.0f;

    #pragma unroll
    for (int s = 0; s < 4; s++) {
        const int slot = ((4 * s + q) ^ (m & 7)) * 8;
        #pragma unroll
        for (int nf = 0; nf < 16; nf++) {
            const short8 b = *(const short8*)&Bb[(nf * 16 + m) * 128 + slot];
            acc[0][nf] = __builtin_amdgcn_mfma_f32_16x16x32_bf16(a[0][s], b, acc[0][nf], 0, 0, 0);
            acc[1][nf] = __builtin_amdgcn_mfma_f32_16x16x32_bf16(a[1][s], b, acc[1][nf], 0, 0, 0);
        }
    }

    float kll = 0.0f;
    #pragma unroll
    for (int a2 = 0; a2 < 2; a2++)
        #pragma unroll
        for (int nf = 0; nf < 8; nf++) {
            int col = nf * 16 + m;
            float bm = b2[col], bl = b2[col + 128];
            #pragma unroll
            for (int r = 0; r < 4; r++) {
                int node = wbase + a2 * 16 + q * 4 + r;
                float mu = acc[a2][nf][r] + bm;
                float lv = tanhf(acc[a2][nf + 8][r] + bl);
                float e  = eps[(size_t)node * 128 + col];
                z_bf[(size_t)node * 128 + col] = f2bf(mu + expf(0.5f * lv) * e);
                kll += lv + 1.0f - expf(lv) - mu * mu;
            }
        }
    #pragma unroll
    for (int off = 32; off > 0; off >>= 1) kll += __shfl_down(kll, off);
    if (lane == 0) atomicAdd(kl_sum, kll);
}

// ---------------- CSR build ----------------
__global__ void hist_kernel(const int* __restrict__ edst, int* __restrict__ cnt)
{
    int e = blockIdx.x * 256 + threadIdx.x;
    if (e < NE) atomicAdd(&cnt[edst[e]], 1);
}

__global__ void scan1_kernel(const int* __restrict__ cnt, int* __restrict__ bsum)
{
    __shared__ int ls[256];
    int b = blockIdx.x, tid = threadIdx.x;
    int idx0 = b * 1024 + tid * 4;
    int s = 0;
    #pragma unroll
    for (int i = 0; i < 4; i++) { int idx = idx0 + i; if (idx < NN) s += cnt[idx]; }
    ls[tid] = s; __syncthreads();
    for (int off = 128; off > 0; off >>= 1) {
        if (tid < off) ls[tid] += ls[tid + off];
        __syncthreads();
    }
    if (tid == 0) bsum[b] = ls[0];
}

__global__ void scan2_kernel(int* __restrict__ bsum, int* __restrict__ rowstart)
{
    __shared__ int ls[512];
    int tid = threadIdx.x;
    int v = (tid < NBLK_SCAN) ? bsum[tid] : 0;
    ls[tid] = v; __syncthreads();
    for (int off = 1; off < 512; off <<= 1) {
        int t = 0;
        if (tid >= off) t = ls[tid - off];
        __syncthreads();
        ls[tid] += t;
        __syncthreads();
    }
    if (tid < NBLK_SCAN) bsum[tid] = (tid == 0) ? 0 : ls[tid - 1];
    if (tid == 0) rowstart[NN] = NE;
}

__global__ void scan3_kernel(const int* __restrict__ cnt, const int* __restrict__ bsum,
                             int* __restrict__ rowstart, int* __restrict__ cursor)
{
    __shared__ int ls[256];
    int b = blockIdx.x, tid = threadIdx.x;
    int idx0 = b * 1024 + tid * 4;
    int v[4]; int s = 0;
    #pragma unroll
    for (int i = 0; i < 4; i++) { int idx = idx0 + i; v[i] = (idx < NN) ? cnt[idx] : 0; s += v[i]; }
    ls[tid] = s; __syncthreads();
    for (int off = 1; off < 256; off <<= 1) {
        int t = 0;
        if (tid >= off) t = ls[tid - off];
        __syncthreads();
        ls[tid] += t;
        __syncthreads();
    }
    int ex = ls[tid] - s + bsum[b];
    #pragma unroll
    for (int i = 0; i < 4; i++) {
        int idx = idx0 + i;
        if (idx < NN) { rowstart[idx] = ex; cursor[idx] = ex; }
        ex += v[i];
    }
}

__global__ void fill_kernel(const int* __restrict__ esrc, const int* __restrict__ edst,
                            int* __restrict__ cursor, int* __restrict__ csr)
{
    int e = blockIdx.x * 256 + threadIdx.x;
    if (e < NE) {
        int pos = atomicAdd(&cursor[edst[e]], 1);
        csr[pos] = esrc[e];
    }
}

// ---------------- dec: fused gather + dual GEMM + MFMA heads + loss ----------------
__global__ __launch_bounds__(256, 2) void dec_mfma(
    const short* __restrict__ z_bf, const int* __restrict__ rowstart, const int* __restrict__ csr,
    const short* __restrict__ Wds0, const short* __restrict__ Wds1, const short* __restrict__ HWp,
    const float* __restrict__ mub, const float* __restrict__ lvb,
    const float* __restrict__ opwise, const int* __restrict__ op_id,
    const float* __restrict__ lat,
    float* __restrict__ op_loss, float* __restrict__ op_cnt,
    float* __restrict__ loss_sum)
{
    __shared__ __align__(16) short regionA[128 * 128];   // 32 KB: agg (swizzled) -> yd (swizzled)
    __shared__ __align__(16) char  regionB[32768];       // Wself -> Wagg -> {hw | mlv}
    short* Bb  = (short*)regionB;
    short* hw  = (short*)regionB;                        // [16][136] after GEMM
    float* mlv = (float*)(regionB + 4608);               // [128][16]

    const int tid = threadIdx.x;
    const int lane = tid & 63, w = tid >> 6;
    const int m = lane & 15, q = lane >> 4;
    const int bbase = blockIdx.x * 128;
    const int wbase = bbase + w * 32;
    const bool wv = (wbase < NN);

    // ---- gather agg tile into regionA (swizzled) + stage Wself into Bb ----
    {
        const short8* g = (const short8*)Wds0;
        short8* l = (short8*)Bb;
        #pragma unroll
        for (int i = 0; i < 8; i++) l[tid + 256 * i] = g[tid + 256 * i];
    }
    {
        int nodeL = tid & 127, hh = tid >> 7;
        int n = bbase + nodeL;
        float a[64];
        #pragma unroll
        for (int i = 0; i < 64; i++) a[i] = 0.0f;
        if (n < NN) {
            int r0 = rowstart[n], r1 = rowstart[n + 1];
            for (int e = r0; e < r1; e++) {
                const short8* zp = (const short8*)(z_bf + (size_t)csr[e] * 128 + hh * 64);
                #pragma unroll
                for (int j = 0; j < 8; j++) {
                    short8 v = zp[j];
                    #pragma unroll
                    for (int i = 0; i < 8; i++) a[j * 8 + i] += bf2f(v[i]);
                }
            }
        }
        #pragma unroll
        for (int j = 0; j < 8; j++) {
            int slot = ((hh * 8 + j) ^ (nodeL & 7)) * 8;
            short8 o;
            #pragma unroll
            for (int i = 0; i < 8; i++) o[i] = f2bf(a[j * 8 + i]);
            *(short8*)&regionA[nodeL * 128 + slot] = o;
        }
    }
    __syncthreads();

    f32x4 acc[2][8];
    #pragma unroll
    for (int a2 = 0; a2 < 2; a2++)
        #pragma unroll
        for (int nf = 0; nf < 8; nf++) acc[a2][nf] = (f32x4)0.0f;

    // ---- phase 1: z @ Wself ----
    if (wv) {
        short8 az[2][4];
        #pragma unroll
        for (int s = 0; s < 4; s++) {
            az[0][s] = *(const short8*)(z_bf + (size_t)(wbase + m) * 128 + s * 32 + q * 8);
            az[1][s] = *(const short8*)(z_bf + (size_t)(wbase + 16 + m) * 128 + s * 32 + q * 8);
        }
        #pragma unroll
        for (int s = 0; s < 4; s++) {
            const int slot = ((4 * s + q) ^ (m & 7)) * 8;
            #pragma unroll
            for (int nf = 0; nf < 8; nf++) {
                const short8 b = *(const short8*)&Bb[(nf * 16 + m) * 128 + slot];
                acc[0][nf] = __builtin_amdgcn_mfma_f32_16x16x32_bf16(az[0][s], b, acc[0][nf], 0, 0, 0);
                acc[1][nf] = __builtin_amdgcn_mfma_f32_16x16x32_bf16(az[1][s], b, acc[1][nf], 0, 0, 0);
            }
        }
    }
    __syncthreads();

    // ---- stage Wagg ----
    {
        const short8* g = (const short8*)Wds1;
        short8* l = (short8*)Bb;
        #pragma unroll
        for (int i = 0; i < 8; i++) l[tid + 256 * i] = g[tid + 256 * i];
    }
    __syncthreads();

    // ---- phase 2: agg @ Wagg (A from regionA, swizzled) ----
    if (wv) {
        #pragma unroll
        for (int s = 0; s < 4; s++) {
            const int slot = ((4 * s + q) ^ (m & 7)) * 8;
            const short8 a0 = *(const short8*)&regionA[(w * 32 + m) * 128 + slot];
            const short8 a1 = *(const short8*)&regionA[(w * 32 + 16 + m) * 128 + slot];
            #pragma unroll
            for (int nf = 0; nf < 8; nf++) {
                const short8 b = *(const short8*)&Bb[(nf * 16 + m) * 128 + slot];
                acc[0][nf] = __builtin_amdgcn_mfma_f32_16x16x32_bf16(a0, b, acc[0][nf], 0, 0, 0);
                acc[1][nf] = __builtin_amdgcn_mfma_f32_16x16x32_bf16(a1, b, acc[1][nf], 0, 0, 0);
            }
        }
    }
    __syncthreads();

    // ---- yd = relu(acc) -> regionA (swizzled); stage head weights ----
    if (wv) {
        #pragma unroll
        for (int a2 = 0; a2 < 2; a2++)
            #pragma unroll
            for (int nf = 0; nf < 8; nf++) {
                int c = nf * 2 + (m >> 3);
                #pragma unroll
                for (int r = 0; r < 4; r++) {
                    int node = w * 32 + a2 * 16 + q * 4 + r;
                    regionA[node * 128 + ((c ^ (node & 7)) * 8) + (m & 7)] =
                        f2bf(fmaxf(acc[a2][nf][r], 0.0f));
                }
            }
    }
    {
        int nn = tid >> 4, c = tid & 15;
        *(short8*)&hw[nn * 136 + c * 8] = *(const short8*)(HWp + nn * 128 + c * 8);
    }
    __syncthreads();

    // ---- heads via MFMA: [mu|lv](128x16) = yd(128x128) @ HW^T ----
    if (wv) {
        f32x4 h0 = (f32x4)0.0f, h1 = (f32x4)0.0f;
        #pragma unroll
        for (int s2 = 0; s2 < 4; s2++) {
            const int slot = ((4 * s2 + q) ^ (m & 7)) * 8;
            short8 a0 = *(const short8*)&regionA[(w * 32 + m) * 128 + slot];
            short8 a1 = *(const short8*)&regionA[(w * 32 + 16 + m) * 128 + slot];
            short8 b  = *(const short8*)&hw[m * 136 + s2 * 32 + q * 8];
            h0 = __builtin_amdgcn_mfma_f32_16x16x32_bf16(a0, b, h0, 0, 0, 0);
            h1 = __builtin_amdgcn_mfma_f32_16x16x32_bf16(a1, b, h1, 0, 0, 0);
        }
        float hb = (m < 8) ? mub[m] : lvb[m - 8];
        #pragma unroll
        for (int r = 0; r < 4; r++) {
            mlv[(w * 32 + q * 4 + r) * 16 + m]      = h0[r] + hb;
            mlv[(w * 32 + 16 + q * 4 + r) * 16 + m] = h1[r] + hb;
        }
    }
    __syncthreads();

    // ---- per-node loss + segment sums ----
    float lsum = 0.0f;
    if (tid < 128 && bbase + tid < NN) {
        const int t = tid;
        const int n = bbase + t;
        const int op = op_id[n];
        const float4* w4 = (const float4*)(opwise + (size_t)op * 128);
        float mout[8], lout[8];
        #pragma unroll
        for (int k = 0; k < 8; k++) { mout[k] = 0.0f; lout[k] = 0.0f; }
        #pragma unroll
        for (int l = 0; l < 8; l++) {
            float mv = mlv[t * 16 + l];
            float vv = mlv[t * 16 + 8 + l];
            float4 a = w4[l * 4 + 0];
            float4 b = w4[l * 4 + 1];
            float4 c = w4[l * 4 + 2];
            float4 d = w4[l * 4 + 3];
            mout[0] = fmaf(mv, a.x, mout[0]); mout[1] = fmaf(mv, a.y, mout[1]);
            mout[2] = fmaf(mv, a.z, mout[2]); mout[3] = fmaf(mv, a.w, mout[3]);
            mout[4] = fmaf(mv, b.x, mout[4]); mout[5] = fmaf(mv, b.y, mout[5]);
            mout[6] = fmaf(mv, b.z, mout[6]); mout[7] = fmaf(mv, b.w, mout[7]);
            lout[0] = fmaf(vv, c.x, lout[0]); lout[1] = fmaf(vv, c.y, lout[1]);
            lout[2] = fmaf(vv, c.z, lout[2]); lout[3] = fmaf(vv, c.w, lout[3]);
            lout[4] = fmaf(vv, d.x, lout[4]); lout[5] = fmaf(vv, d.y, lout[5]);
            lout[6] = fmaf(vv, d.z, lout[6]); lout[7] = fmaf(vv, d.w, lout[7]);
        }
        const float4* lp = (const float4*)(lat + (size_t)n * 8);
        float4 lb0 = lp[0], lb1 = lp[1];
        float labels[8] = {lb0.x, lb0.y, lb0.z, lb0.w, lb1.x, lb1.y, lb1.z, lb1.w};
        float lnode = 0.0f;
        #pragma unroll
        for (int k = 0; k < 8; k++) {
            float diff = mout[k] - labels[k];
            lnode += diff * diff / (2.0f * expf(lout[k]) + 1e-7f) + 0.5f * lout[k];
        }
        lnode *= 0.125f;
        atomicAdd(&op_loss[op], lnode);
        atomicAdd(&op_cnt[op], 1.0f);
        lsum = lnode;
    }
    #pragma unroll
    for (int off = 32; off > 0; off >>= 1) lsum += __shfl_down(lsum, off);
    if (lane == 0) atomicAdd(loss_sum, lsum);
}

// ---------------- finalize ----------------
__global__ void final_kernel(const float* __restrict__ accum, float* __restrict__ out)
{
    out[0] = accum[1] / (float)NN - 0.5f * (accum[0] / (float)((size_t)NN * 128));
}

extern "C" void kernel_launch(void* const* d_in, const int* in_sizes, int n_in,
                              void* d_out, int out_size, void* d_ws, size_t ws_size,
                              hipStream_t stream) {
    const int*   op_id  = (const int*)  d_in[0];
    const int*   sv_id  = (const int*)  d_in[1];
    const int*   st_id  = (const int*)  d_in[2];
    const float* lat    = (const float*)d_in[3];
    const int*   esrc   = (const int*)  d_in[4];
    const int*   edst   = (const int*)  d_in[5];
    const float* eps    = (const float*)d_in[6];
    const float* opE    = (const float*)d_in[7];
    const float* svE    = (const float*)d_in[8];
    const float* stE    = (const float*)d_in[9];
    const float* W1     = (const float*)d_in[10];
    const float* b1     = (const float*)d_in[11];
    const float* W2     = (const float*)d_in[12];
    const float* b2     = (const float*)d_in[13];
    const float* Wself  = (const float*)d_in[14];
    const float* Wagg   = (const float*)d_in[15];
    const float* muW    = (const float*)d_in[16];
    const float* mub    = (const float*)d_in[17];
    const float* lvW    = (const float*)d_in[18];
    const float* lvb    = (const float*)d_in[19];
    const float* opwise = (const float*)d_in[20];

    char* wsb = (char*)d_ws;
    short* W1s      = (short*)(wsb + 0);              // 65536 B
    short* W2s      = (short*)(wsb + 65536);          // 65536 B
    short* Wds0     = (short*)(wsb + 131072);         // 32768 B
    short* Wds1     = (short*)(wsb + 163840);         // 32768 B
    short* HWp      = (short*)(wsb + 196608);         // 4096 B
    float* accum    = (float*)(wsb + 204800);         // 8 B: [0]=kl, [1]=loss
    int*   cnt      = (int*)  (wsb + (4  << 20));
    int*   rowstart = (int*)  (wsb + (6  << 20));
    int*   cursor   = (int*)  (wsb + (9  << 20));
    int*   csr      = (int*)  (wsb + (12 << 20));
    int*   bsum     = (int*)  (wsb + (16 << 20));
    short* h_bf     = (short*)(wsb + (32  << 20));    // 128 MB
    short* z_bf     = (short*)(wsb + (160ull << 20)); // 128 MB
    float* out      = (float*)d_out;

    hipMemsetAsync(d_out, 0, (size_t)out_size * sizeof(float), stream);
    hipMemsetAsync(accum, 0, 2 * sizeof(float), stream);
    hipMemsetAsync(cnt, 0, (size_t)NN * sizeof(int), stream);

    prep_kernel<<<128, 256, 0, stream>>>(W1, W2, Wself, Wagg, muW, lvW,
                                         W1s, W2s, Wds0, Wds1, HWp);

    hist_kernel<<<(NE + 255) / 256, 256, 0, stream>>>(edst, cnt);
    scan1_kernel<<<NBLK_SCAN, 256, 0, stream>>>(cnt, bsum);
    scan2_kernel<<<1, 512, 0, stream>>>(bsum, rowstart);
    scan3_kernel<<<NBLK_SCAN, 256, 0, stream>>>(cnt, bsum, rowstart, cursor);
    fill_kernel<<<(NE + 255) / 256, 256, 0, stream>>>(esrc, edst, cursor, csr);

    enc1_mfma<<<NBLK, 256, 0, stream>>>(op_id, sv_id, st_id, lat, opE, svE, stE, W1s, b1, h_bf);
    enc2_mfma<<<NBLK, 256, 0, stream>>>(h_bf, W2s, b2, eps, z_bf, accum + 0);
    dec_mfma<<<NBLK, 256, 0, stream>>>(z_bf, rowstart, csr, Wds0, Wds1, HWp, mub, lvb,
                                       opwise, op_id, lat,
                                       out + 1, out + 1 + OPC, accum + 1);
    final_kernel<<<1, 1, 0, stream>>>(accum, out);
}